// Round 11
// baseline (670.470 us; speedup 1.0000x reference)
//
#include <hip/hip_runtime.h>
#include <hip/hip_bf16.h>

typedef unsigned short u16;
typedef unsigned int u32;
typedef __attribute__((ext_vector_type(8))) short s8v;   // 8 x bf16
typedef __attribute__((ext_vector_type(4))) float f4v;   // mfma acc

__device__ __forceinline__ float b2f(u16 u) {
  union { u32 i; float f; } v; v.i = ((u32)u) << 16; return v.f;
}
__device__ __forceinline__ u16 f2b(float f) {
  union { float f; u32 i; } v; v.f = f;
  u32 r = v.i + 0x7FFFu + ((v.i >> 16) & 1u);
  return (u16)(r >> 16);
}
__device__ __forceinline__ float rcpf(float x) { return __builtin_amdgcn_rcpf(x); }
__device__ __forceinline__ float ex2(float x) {
#if __has_builtin(__builtin_amdgcn_exp2f)
  return __builtin_amdgcn_exp2f(x);
#else
  return exp2f(x);
#endif
}
__device__ __forceinline__ float sigf(float x) { return rcpf(1.0f + __expf(-x)); }

#define GS_IFO 1.4426950408889634f
#define GS_G   2.8853900817779268f

__device__ __forceinline__ void gl_lds16(const u16* g, u16* l) {
  __builtin_amdgcn_global_load_lds(
      (const __attribute__((address_space(1))) u32*)g,
      (__attribute__((address_space(3))) u32*)l, 16, 0, 0);
}

// ---------------- weight conversion fp32 -> bf16 ----------------
// scl: 0 none, 1 gate-pattern scale (exp2 domain), 2 uniform log2e. sh: log2(float4s/row).
struct CvtArgs {
  const float* src[9];
  u16* dst[9];
  int n4[9];
  int scl[9];
  int sh[9];
};
__global__ __launch_bounds__(256) void k_cvt(CvtArgs a) {
  int seg = blockIdx.y;
  int i = blockIdx.x * 256 + threadIdx.x;
  if (i >= a.n4[seg]) return;
  float4 v = ((const float4*)a.src[seg])[i];
  if (a.scl[seg]) {
    float s;
    if (a.scl[seg] == 2) {
      s = GS_IFO;
    } else {
      int r = i >> a.sh[seg];
      s = (((r >> 7) & 3) == 2) ? GS_G : GS_IFO;
    }
    v.x *= s; v.y *= s; v.z *= s; v.w *= s;
  }
  ushort4 o;
  o.x = f2b(v.x); o.y = f2b(v.y); o.z = f2b(v.z); o.w = f2b(v.w);
  ((ushort4*)a.dst[seg])[i] = o;
}

// ------- transpose input [B,C,H,W] -> A_h bf16 [(b,w,h)][c]; also channel means -------
__global__ __launch_bounds__(256) void k_tin(const float* __restrict__ in,
                                             u16* __restrict__ A,
                                             float* __restrict__ meansum) {
  int b = blockIdx.z, h = blockIdx.y, c0 = blockIdx.x * 64;
  int t = threadIdx.x, lane = t & 63, q = t >> 6;
  __shared__ u16 lT[64][66];
  const float* src = in + ((b * 256 + c0) * 64 + h) * 64;
#pragma unroll 4
  for (int i = 0; i < 16; ++i) {
    int cl = q * 16 + i;
    float v = src[cl * 4096 + lane];
    lT[cl][lane] = f2b(v);
    float s = v;
#pragma unroll
    for (int off = 32; off; off >>= 1) s += __shfl_xor(s, off);
    if (lane == 0) atomicAdd(&meansum[b * 256 + c0 + cl], s);
  }
  __syncthreads();
  u16* dst = A + (b * 4096 + h) * 256 + c0;
#pragma unroll 4
  for (int i = 0; i < 16; ++i) {
    int w = q * 16 + i;
    dst[w * 16384 + lane] = lT[lane][w];
  }
}

// ------- q_avg[b][o] = softmax_o( Wl[o,:] . mean_c ) -------
__global__ __launch_bounds__(256) void k_qavg(const float* __restrict__ meansum,
                                              const float* __restrict__ Wl,
                                              float* __restrict__ qavg) {
  int b = blockIdx.x, t = threadIdx.x;
  __shared__ float mean[256];
  __shared__ float red[256];
  mean[t] = meansum[b * 256 + t] * (1.0f / 4096.0f);
  __syncthreads();
  const float* wr = Wl + t * 256;
  float acc = 0.0f;
  for (int c = 0; c < 256; ++c) acc = fmaf(wr[c], mean[c], acc);
  red[t] = acc; __syncthreads();
  for (int s = 128; s; s >>= 1) { if (t < s) red[t] = fmaxf(red[t], red[t + s]); __syncthreads(); }
  float mx = red[0]; __syncthreads();
  float e = __expf(acc - mx);
  red[t] = e; __syncthreads();
  for (int s = 128; s; s >>= 1) { if (t < s) red[t] += red[t + s]; __syncthreads(); }
  qavg[b * 256 + t] = e / red[0];
}

// ------- 128x128-tile bf16 MFMA GEMM (only used for Wr now, with Zsum epilogue) -------
__global__ __launch_bounds__(256, 4) void k_gemm2(const u16* __restrict__ A,
                                                  const u16* __restrict__ W,
                                                  u16* __restrict__ out, int nstride, int NT,
                                                  float* __restrict__ Zsum) {
  int nwg = gridDim.x;
  int q = nwg >> 3;
  int bid = blockIdx.x;
  int swz = (bid & 7) * q + (bid >> 3);
  int mt = swz / NT, nt = swz % NT;
  int mb = mt << 7, nb = nt << 7;
  int t = threadIdx.x, lane = t & 63, wid = t >> 6;
  int laneg = lane & 15, lk = lane >> 4;
  __shared__ __align__(16) u16 lA[128][64];
  __shared__ __align__(16) u16 lW[128][64];
  f4v acc[4][4] = {};
  int wm = wid >> 1, wn = wid & 1;
  for (int kb = 0; kb < 4; ++kb) {
    if (kb) __syncthreads();
#pragma unroll
    for (int k = 0; k < 4; ++k) {
      int rb = (wid << 5) + (k << 3);
      int r = rb + (lane >> 3);
      int cs = (lane & 7) ^ (r & 7);
      const u16* ga = A + (mb + r) * 256 + (kb << 6) + (cs << 3);
      const u16* gw = W + (nb + r) * 256 + (kb << 6) + (cs << 3);
      gl_lds16(ga, &lA[rb][0]);
      gl_lds16(gw, &lW[rb][0]);
    }
    __syncthreads();
#pragma unroll
    for (int kk = 0; kk < 2; ++kk) {
      s8v af[4], bf[4];
#pragma unroll
      for (int m = 0; m < 4; ++m) {
        int r = (wm << 6) + (m << 4) + laneg;
        int c = ((kk << 2) + lk) ^ (r & 7);
        af[m] = *(const s8v*)&lA[r][c << 3];
      }
#pragma unroll
      for (int n = 0; n < 4; ++n) {
        int r = (wn << 6) + (n << 4) + laneg;
        int c = ((kk << 2) + lk) ^ (r & 7);
        bf[n] = *(const s8v*)&lW[r][c << 3];
      }
#pragma unroll
      for (int m = 0; m < 4; ++m)
#pragma unroll
        for (int n = 0; n < 4; ++n)
          acc[m][n] = __builtin_amdgcn_mfma_f32_16x16x32_bf16(af[m], bf[n], acc[m][n], 0, 0, 0);
    }
  }
#pragma unroll
  for (int n = 0; n < 4; ++n) {
    int col = nb + (wn << 6) + (n << 4) + laneg;
    float csum = 0.f;
#pragma unroll
    for (int m = 0; m < 4; ++m) {
      int row0 = mb + (wm << 6) + (m << 4) + (lk << 2);
#pragma unroll
      for (int j = 0; j < 4; ++j) {
        float e = ex2(acc[m][n][j]);
        csum += e;
        out[(row0 + j) * nstride + col] = f2b(e);
      }
    }
    csum += __shfl_xor(csum, 16);
    csum += __shfl_xor(csum, 32);
    if (lk == 0) atomicAdd(&Zsum[((mb >> 12) << 8) + col], csum);
  }
}

// ------- FUSED bidirectional LSTM v4: software-pipelined Wih·x (nacc carried one step
//         ahead); LDS x staging (3 buffers); mid-step vmcnt(4); lgkm-only barrier. -------
// X: bf16 [s*64+t][256]; Wih: [2][512][256] scaled; Whh: [2][512][128] scaled;
// outb row = (s/64)*4096 + t*64 + s%64, cols [dir*128, dir*128+128).
__global__ __launch_bounds__(512, 2) void k_recur_f(const u16* __restrict__ X,
                                                    const u16* __restrict__ Wih,
                                                    const u16* __restrict__ Whh,
                                                    const float* __restrict__ bias_f,
                                                    const float* __restrict__ bias_b,
                                                    u16* __restrict__ outb) {
  int dir = blockIdx.y;
  int s0 = blockIdx.x << 4;                 // 16 sequences per block
  int t = threadIdx.x, lane = t & 63, w = t >> 6;  // 8 waves
  int laneg = lane & 15, lk = lane >> 4;
  const u16* Wd = Whh + dir * 65536;
  const u16* Wi = Wih + dir * 131072;
  const float* bia = dir ? bias_b : bias_f;
  int hc = w << 4;
  // Whh B-fragments (K=128)
  s8v bfr[4][4];
#pragma unroll
  for (int g = 0; g < 4; ++g)
#pragma unroll
    for (int kk = 0; kk < 4; ++kk)
      bfr[g][kk] = *(const s8v*)(Wd + (g * 128 + hc + laneg) * 128 + kk * 32 + lk * 8);
  // Wih B-fragments (K=256)
  s8v ifr[4][8];
#pragma unroll
  for (int g = 0; g < 4; ++g)
#pragma unroll
    for (int kk = 0; kk < 8; ++kk)
      ifr[g][kk] = *(const s8v*)(Wi + (g * 128 + hc + laneg) * 256 + kk * 32 + lk * 8);
  float bval[4];
#pragma unroll
  for (int g = 0; g < 4; ++g)
    bval[g] = bia[g * 128 + hc + laneg] * ((g == 2) ? GS_G : GS_IFO);

  __shared__ __align__(16) u16 hb[2][16][136];
  __shared__ __align__(16) u16 xb[3][16][256];
  for (int i = t; i < 2 * 16 * 136; i += 512) ((u16*)hb)[i] = 0;

  float cs[4] = {0.f, 0.f, 0.f, 0.f};
  int tc0 = dir ? 63 : 0;
  int dstep = dir ? -1 : 1;
  // x staging: thread stages 16B of LDS row srow, chunk schunk (inverse-swizzled source)
  int srow = (w << 1) + (lane >> 5);        // 0..15
  int schunk = lane & 31;                   // 0..31 (16B chunks)
  const u16* xsrc = X + (s0 + srow) * 64 * 256 + ((schunk ^ (srow & 7)) << 3);
  int rowb = ((s0 >> 6) << 12) + (s0 & 63);
  u16* obase = outb + (dir << 7);
  // prologue: stage x(t0)->xb[0], x(t0+1)->xb[1], x(t0+2)->xb[2]; full drain once.
  gl_lds16(xsrc + tc0 * 256, &xb[0][w << 1][0]);
  gl_lds16(xsrc + ((tc0 + dstep) & 63) * 256, &xb[1][w << 1][0]);
  gl_lds16(xsrc + ((tc0 + 2 * dstep) & 63) * 256, &xb[2][w << 1][0]);
  __syncthreads();
  // prologue: nacc = bias + Wih.x(t0)  (consumed at st=0)
  f4v nacc[4];
#pragma unroll
  for (int g = 0; g < 4; ++g)
    nacc[g] = (f4v){bval[g], bval[g], bval[g], bval[g]};
  {
    const u16* xrow = &xb[0][laneg][0];
    s8v xf[8];
#pragma unroll
    for (int kk = 0; kk < 8; ++kk)
      xf[kk] = *(const s8v*)&xrow[((kk * 4 + lk) ^ (laneg & 7)) << 3];
#pragma unroll
    for (int g = 0; g < 4; ++g)
#pragma unroll
      for (int kk = 0; kk < 8; ++kk)
        nacc[g] = __builtin_amdgcn_mfma_f32_16x16x32_bf16(xf[kk], ifr[g][kk], nacc[g], 0, 0, 0);
  }
  int cur = 0;
  for (int st = 0; st < 64; ++st) {
    int tc = tc0 + st * dstep;
    // 0. take over the pipelined accumulator (already bias + Wih.x_t)
    f4v acc[4];
#pragma unroll
    for (int g = 0; g < 4; ++g) acc[g] = nacc[g];
    // 1. store h of previous step (reads hb[cur]; this step's writes go to hb[cur^1])
    if (st) {
      int pr = tc - dstep;
      uint2 hv = *(const uint2*)&hb[cur][srow][schunk << 2];
      *(uint2*)(obase + (rowb + pr * 64 + srow) * 256 + (schunk << 2)) = hv;
    }
    // 2. prefetch x(t+3) into xb[st%3] (its last reader was step st-1; barrier passed)
    {
      int tn = (tc0 + (st + 3) * dstep) & 63;   // wraps at tail; garbage unused
      gl_lds16(xsrc + tn * 256, &xb[st % 3][w << 1][0]);
    }
    // 3. serial chain part 1: Whh·h
    {
      s8v afr[4];
#pragma unroll
      for (int kk = 0; kk < 4; ++kk)
        afr[kk] = *(const s8v*)&hb[cur][laneg][kk * 32 + lk * 8];
#pragma unroll
      for (int g = 0; g < 4; ++g)
#pragma unroll
        for (int kk = 0; kk < 4; ++kk)
          acc[g] = __builtin_amdgcn_mfma_f32_16x16x32_bf16(afr[kk], bfr[g][kk], acc[g], 0, 0, 0);
    }
    // 4. INDEPENDENT work: nacc = bias + Wih.x_{t+1} (overlaps chain latency).
    //    xb[(st+1)%3] written by gl_lds at step st-2 (or prologue); vmcnt(4) leaves the
    //    4 newer VMEM ops (gl@st-1, store@st-1/st, gl@st) in flight — in-order counter.
    if (st < 63) {
      asm volatile("s_waitcnt vmcnt(4)" ::: "memory");
#pragma unroll
      for (int g = 0; g < 4; ++g)
        nacc[g] = (f4v){bval[g], bval[g], bval[g], bval[g]};
      const u16* xrow = &xb[(st + 1) % 3][laneg][0];
      s8v xf[8];
#pragma unroll
      for (int kk = 0; kk < 8; ++kk)
        xf[kk] = *(const s8v*)&xrow[((kk * 4 + lk) ^ (laneg & 7)) << 3];
#pragma unroll
      for (int g = 0; g < 4; ++g)
#pragma unroll
        for (int kk = 0; kk < 8; ++kk)
          nacc[g] = __builtin_amdgcn_mfma_f32_16x16x32_bf16(xf[kk], ifr[g][kk], nacc[g], 0, 0, 0);
    }
    // 5. serial chain part 2: gates
    int nxt = cur ^ 1;
#pragma unroll
    for (int j = 0; j < 4; ++j) {
      float iv = rcpf(1.0f + ex2(-acc[0][j]));
      float fv = rcpf(1.0f + ex2(-acc[1][j]));
      float gv = 1.0f - 2.0f * rcpf(1.0f + ex2(acc[2][j]));
      float ov = rcpf(1.0f + ex2(-acc[3][j]));
      float c = fv * cs[j] + iv * gv;
      cs[j] = c;
      float th = 1.0f - 2.0f * rcpf(1.0f + ex2(c * GS_G));
      hb[nxt][lk * 4 + j][hc + laneg] = f2b(ov * th);
    }
    // 6. LDS-only barrier (global write-acks and young prefetches stay in flight)
    asm volatile("s_waitcnt lgkmcnt(0)" ::: "memory");
    __builtin_amdgcn_s_barrier();
    cur = nxt;
  }
  // final h store
  {
    int pr = tc0 + 63 * dstep;
    uint2 hv = *(const uint2*)&hb[cur][srow][schunk << 2];
    *(uint2*)(obase + (rowb + pr * 64 + srow) * 256 + (schunk << 2)) = hv;
  }
}

// ------- fused attention + final: att = (qavg/Z) . evf ; out = in*(1+al*sig(att)) -------
__global__ __launch_bounds__(256) void k_attfin(const u16* __restrict__ VF,
                                                const float* __restrict__ qavg,
                                                const float* __restrict__ Z,
                                                const float* __restrict__ in,
                                                const float* __restrict__ alpha,
                                                float* __restrict__ out) {
  int bx = blockIdx.x;
  int b = bx >> 6;
  int sp0 = (bx & 63) << 6;
  int t = threadIdx.x, lane = t & 63, wid = t >> 6;
  __shared__ __align__(16) float lwo[256];
  __shared__ float fac[64];
  lwo[t] = qavg[b * 256 + t] / Z[b * 256 + t];
  __syncthreads();
  float4 wo = *(const float4*)&lwo[lane * 4];
  int rowbase = b * 4096 + sp0;
#pragma unroll 4
  for (int i = 0; i < 16; ++i) {
    int r = wid * 16 + i;
    uint2 v = *(const uint2*)&VF[(rowbase + r) * 256 + lane * 4];
    float x0 = b2f((u16)(v.x & 0xffff)), x1 = b2f((u16)(v.x >> 16));
    float x2 = b2f((u16)(v.y & 0xffff)), x3 = b2f((u16)(v.y >> 16));
    float p = wo.x * x0 + wo.y * x1 + wo.z * x2 + wo.w * x3;
#pragma unroll
    for (int off = 32; off; off >>= 1) p += __shfl_xor(p, off);
    if (lane == 0) fac[r] = p;
  }
  __syncthreads();
  float al = alpha[0];
  if (t < 64) fac[t] = 1.0f + al * sigf(fac[t]);
  __syncthreads();
  int sp = t & 63;
  float f = fac[sp];
  const float* ip = in + (long)b * 1048576 + sp0 + sp;
  float* op = out + (long)b * 1048576 + sp0 + sp;
  int c0 = t >> 6;
#pragma unroll 8
  for (int c = c0; c < 256; c += 4) {
    op[c * 4096] = ip[c * 4096] * f;
  }
}

extern "C" void kernel_launch(void* const* d_in, const int* in_sizes, int n_in,
                              void* d_out, int out_size, void* d_ws, size_t ws_size,
                              hipStream_t stream) {
  const float* input   = (const float*)d_in[0];
  const float* h_Wih_f = (const float*)d_in[1];
  const float* h_Whh_f = (const float*)d_in[2];
  const float* h_b_f   = (const float*)d_in[3];
  const float* h_Wih_b = (const float*)d_in[4];
  const float* h_Whh_b = (const float*)d_in[5];
  const float* h_b_b   = (const float*)d_in[6];
  const float* v_Wih_f = (const float*)d_in[7];
  const float* v_Whh_f = (const float*)d_in[8];
  const float* v_b_f   = (const float*)d_in[9];
  const float* v_Wih_b = (const float*)d_in[10];
  const float* v_Whh_b = (const float*)d_in[11];
  const float* v_b_b   = (const float*)d_in[12];
  const float* Wr      = (const float*)d_in[13];
  const float* Wl      = (const float*)d_in[14];
  const float* alphap  = (const float*)d_in[15];

  char* ws = (char*)d_ws;
  u16* Ah     = (u16*)(ws + 0);            // 33,554,432 B  (x for horizontal; later Ar)
  u16* VF     = (u16*)(ws + 33554432);     // 33,554,432 B
  u16* Wh     = (u16*)(ws + 167772160);    // [2][512][256] bf16
  u16* Wv     = (u16*)(ws + 168296448);    // [2][512][256]
  u16* WhhH   = (u16*)(ws + 168820736);    // [2][512][128]
  u16* WhhV   = (u16*)(ws + 169082880);
  u16* Wrb    = (u16*)(ws + 169345024);    // [256][256]
  float* meansum = (float*)(ws + 169476096);
  float* qavg = (float*)(ws + 169492480);
  float* pZ   = (float*)(ws + 169541632);  // 16 KB softmax denominators
  u16* Av = (u16*)d_out;                   // horizontal biLSTM output (33.5 MB < 64 MB)
  u16* Ar = Ah;

  (void)hipMemsetAsync(meansum, 0, 16 * 256 * 4, stream);
  (void)hipMemsetAsync(pZ, 0, 16 * 256 * 4, stream);

  CvtArgs ca;
  ca.src[0] = h_Wih_f; ca.dst[0] = Wh;          ca.n4[0] = 32768; ca.scl[0] = 1; ca.sh[0] = 6;
  ca.src[1] = h_Wih_b; ca.dst[1] = Wh + 131072; ca.n4[1] = 32768; ca.scl[1] = 1; ca.sh[1] = 6;
  ca.src[2] = v_Wih_f; ca.dst[2] = Wv;          ca.n4[2] = 32768; ca.scl[2] = 1; ca.sh[2] = 6;
  ca.src[3] = v_Wih_b; ca.dst[3] = Wv + 131072; ca.n4[3] = 32768; ca.scl[3] = 1; ca.sh[3] = 6;
  ca.src[4] = h_Whh_f; ca.dst[4] = WhhH;         ca.n4[4] = 16384; ca.scl[4] = 1; ca.sh[4] = 5;
  ca.src[5] = h_Whh_b; ca.dst[5] = WhhH + 65536; ca.n4[5] = 16384; ca.scl[5] = 1; ca.sh[5] = 5;
  ca.src[6] = v_Whh_f; ca.dst[6] = WhhV;         ca.n4[6] = 16384; ca.scl[6] = 1; ca.sh[6] = 5;
  ca.src[7] = v_Whh_b; ca.dst[7] = WhhV + 65536; ca.n4[7] = 16384; ca.scl[7] = 1; ca.sh[7] = 5;
  ca.src[8] = Wr;      ca.dst[8] = Wrb;          ca.n4[8] = 16384; ca.scl[8] = 2; ca.sh[8] = 6;
  k_cvt<<<dim3(128, 9), 256, 0, stream>>>(ca);

  k_tin<<<dim3(4, 64, 16), 256, 0, stream>>>(input, Ah, meansum);
  k_qavg<<<16, 256, 0, stream>>>(meansum, Wl, qavg);

  k_recur_f<<<dim3(64, 2), 512, 0, stream>>>(Ah, Wh, WhhH, h_b_f, h_b_b, Av);
  k_recur_f<<<dim3(64, 2), 512, 0, stream>>>(Av, Wv, WhhV, v_b_f, v_b_b, Ar);
  k_gemm2<<<1024, 256, 0, stream>>>(Ar, Wrb, VF, 256, 2, pZ);

  k_attfin<<<1024, 256, 0, stream>>>(VF, qavg, pZ, input, alphap, (float*)d_out);
}

// Round 13
// 341.361 us; speedup vs baseline: 1.9641x; 1.9641x over previous
//
#include <hip/hip_runtime.h>
#include <hip/hip_bf16.h>

typedef unsigned short u16;
typedef unsigned int u32;
typedef unsigned char u8;
typedef __attribute__((ext_vector_type(8))) short s8v;   // 8 x bf16
typedef __attribute__((ext_vector_type(4))) float f4v;   // mfma acc

__device__ __forceinline__ float b2f(u16 u) {
  union { u32 i; float f; } v; v.i = ((u32)u) << 16; return v.f;
}
__device__ __forceinline__ u16 f2b(float f) {
  union { float f; u32 i; } v; v.f = f;
  u32 r = v.i + 0x7FFFu + ((v.i >> 16) & 1u);
  return (u16)(r >> 16);
}
__device__ __forceinline__ float rcpf(float x) { return __builtin_amdgcn_rcpf(x); }
__device__ __forceinline__ float ex2(float x) {
#if __has_builtin(__builtin_amdgcn_exp2f)
  return __builtin_amdgcn_exp2f(x);
#else
  return exp2f(x);
#endif
}
__device__ __forceinline__ float sigf(float x) { return rcpf(1.0f + __expf(-x)); }
// pack 2 floats -> 2 fp8 e4m3 bytes into low/high 16b word of old (HI must be immediate)
template<bool HI>
__device__ __forceinline__ u32 pkfp8(float a, float b, u32 old) {
  return (u32)__builtin_amdgcn_cvt_pk_fp8_f32(a, b, (int)old, HI);
}

#define GS_IFO 1.4426950408889634f
#define GS_G   2.8853900817779268f

__device__ __forceinline__ void gl_lds16(const void* g, void* l) {
  __builtin_amdgcn_global_load_lds(
      (const __attribute__((address_space(1))) u32*)g,
      (__attribute__((address_space(3))) u32*)l, 16, 0, 0);
}

// ---------------- weight conversion fp32 -> bf16 / fp8 ----------------
// scl: 0 none, 1 gate-pattern (exp2 domain), 2 uniform log2e. sh: log2(float4s/row).
// to8: emit fp8 e4m3 (4 bytes per float4) instead of bf16.
struct CvtArgs {
  const float* src[9];
  void* dst[9];
  int n4[9];
  int scl[9];
  int sh[9];
  int to8[9];
};
__global__ __launch_bounds__(256) void k_cvt(CvtArgs a) {
  int seg = blockIdx.y;
  int i = blockIdx.x * 256 + threadIdx.x;
  if (i >= a.n4[seg]) return;
  float4 v = ((const float4*)a.src[seg])[i];
  if (a.scl[seg]) {
    float s;
    if (a.scl[seg] == 2) {
      s = GS_IFO;
    } else {
      int r = i >> a.sh[seg];
      s = (((r >> 7) & 3) == 2) ? GS_G : GS_IFO;
    }
    v.x *= s; v.y *= s; v.z *= s; v.w *= s;
  }
  if (a.to8[seg]) {
    u32 p = pkfp8<false>(v.x, v.y, 0);
    p = pkfp8<true>(v.z, v.w, p);
    ((u32*)a.dst[seg])[i] = p;
  } else {
    ushort4 o;
    o.x = f2b(v.x); o.y = f2b(v.y); o.z = f2b(v.z); o.w = f2b(v.w);
    ((ushort4*)a.dst[seg])[i] = o;
  }
}

// ------- transpose input [B,C,H,W] -> fp8 x [(b,w,h)][c]; also channel sums -------
__global__ __launch_bounds__(256) void k_tin(const float* __restrict__ in,
                                             u8* __restrict__ A8,
                                             float* __restrict__ meansum) {
  int b = blockIdx.z, h = blockIdx.y, c0 = blockIdx.x * 64;
  int t = threadIdx.x, lane = t & 63, q = t >> 6;
  __shared__ u8 lT[64][68];
  const float* src = in + ((b * 256 + c0) * 64 + h) * 64;
#pragma unroll 4
  for (int i = 0; i < 16; ++i) {
    int cl = q * 16 + i;
    float v = src[cl * 4096 + lane];
    lT[cl][lane] = (u8)(pkfp8<false>(v, v, 0) & 0xffu);
    float s = v;
#pragma unroll
    for (int off = 32; off; off >>= 1) s += __shfl_xor(s, off);
    if (lane == 0) atomicAdd(&meansum[b * 256 + c0 + cl], s);
  }
  __syncthreads();
  u8* dst = A8 + (b * 4096 + h) * 256 + c0;
#pragma unroll 4
  for (int i = 0; i < 16; ++i) {
    int w = q * 16 + i;
    dst[w * 16384 + lane] = lT[lane][w];
  }
}

// ------- q_avg[b][o] = softmax_o( Wl[o,:] . mean_c ) -------
__global__ __launch_bounds__(256) void k_qavg(const float* __restrict__ meansum,
                                              const float* __restrict__ Wl,
                                              float* __restrict__ qavg) {
  int b = blockIdx.x, t = threadIdx.x;
  __shared__ float mean[256];
  __shared__ float red[256];
  mean[t] = meansum[b * 256 + t] * (1.0f / 4096.0f);
  __syncthreads();
  const float* wr = Wl + t * 256;
  float acc = 0.0f;
  for (int c = 0; c < 256; ++c) acc = fmaf(wr[c], mean[c], acc);
  red[t] = acc; __syncthreads();
  for (int s = 128; s; s >>= 1) { if (t < s) red[t] = fmaxf(red[t], red[t + s]); __syncthreads(); }
  float mx = red[0]; __syncthreads();
  float e = __expf(acc - mx);
  red[t] = e; __syncthreads();
  for (int s = 128; s; s >>= 1) { if (t < s) red[t] += red[t + s]; __syncthreads(); }
  qavg[b * 256 + t] = e / red[0];
}

// ------- 128x128-tile bf16 MFMA GEMM (Wr path, with exp2+Zsum epilogue) -------
__global__ __launch_bounds__(256, 4) void k_gemm2(const u16* __restrict__ A,
                                                  const u16* __restrict__ W,
                                                  u16* __restrict__ out, int nstride, int NT,
                                                  float* __restrict__ Zsum) {
  int nwg = gridDim.x;
  int q = nwg >> 3;
  int bid = blockIdx.x;
  int swz = (bid & 7) * q + (bid >> 3);
  int mt = swz / NT, nt = swz % NT;
  int mb = mt << 7, nb = nt << 7;
  int t = threadIdx.x, lane = t & 63, wid = t >> 6;
  int laneg = lane & 15, lk = lane >> 4;
  __shared__ __align__(16) u16 lA[128][64];
  __shared__ __align__(16) u16 lW[128][64];
  f4v acc[4][4] = {};
  int wm = wid >> 1, wn = wid & 1;
  for (int kb = 0; kb < 4; ++kb) {
    if (kb) __syncthreads();
#pragma unroll
    for (int k = 0; k < 4; ++k) {
      int rb = (wid << 5) + (k << 3);
      int r = rb + (lane >> 3);
      int cs = (lane & 7) ^ (r & 7);
      const u16* ga = A + (mb + r) * 256 + (kb << 6) + (cs << 3);
      const u16* gw = W + (nb + r) * 256 + (kb << 6) + (cs << 3);
      gl_lds16(ga, &lA[rb][0]);
      gl_lds16(gw, &lW[rb][0]);
    }
    __syncthreads();
#pragma unroll
    for (int kk = 0; kk < 2; ++kk) {
      s8v af[4], bf[4];
#pragma unroll
      for (int m = 0; m < 4; ++m) {
        int r = (wm << 6) + (m << 4) + laneg;
        int c = ((kk << 2) + lk) ^ (r & 7);
        af[m] = *(const s8v*)&lA[r][c << 3];
      }
#pragma unroll
      for (int n = 0; n < 4; ++n) {
        int r = (wn << 6) + (n << 4) + laneg;
        int c = ((kk << 2) + lk) ^ (r & 7);
        bf[n] = *(const s8v*)&lW[r][c << 3];
      }
#pragma unroll
      for (int m = 0; m < 4; ++m)
#pragma unroll
        for (int n = 0; n < 4; ++n)
          acc[m][n] = __builtin_amdgcn_mfma_f32_16x16x32_bf16(af[m], bf[n], acc[m][n], 0, 0, 0);
    }
  }
#pragma unroll
  for (int n = 0; n < 4; ++n) {
    int col = nb + (wn << 6) + (n << 4) + laneg;
    float csum = 0.f;
#pragma unroll
    for (int m = 0; m < 4; ++m) {
      int row0 = mb + (wm << 6) + (m << 4) + (lk << 2);
#pragma unroll
      for (int j = 0; j < 4; ++j) {
        float e = ex2(acc[m][n][j]);
        csum += e;
        out[(row0 + j) * nstride + col] = f2b(e);
      }
    }
    csum += __shfl_xor(csum, 16);
    csum += __shfl_xor(csum, 32);
    if (lk == 0) atomicAdd(&Zsum[((mb >> 12) << 8) + col], csum);
  }
}

// ------- FUSED biLSTM v5: fp8 x-path (x + Wih in e4m3, fp8 MFMA), bf16 h-path.
//         R9 step structure: 3-buffer distance-2 prefetch, lgkm-only barrier. -------
// X8: fp8 [seq*64+t][256]; Wi8: fp8 [2][512][256] scaled; Whh: bf16 [2][512][128] scaled.
// OUT8: write h as fp8 (for the next biLSTM stage) else bf16 (for the Wr GEMM).
template<bool OUT8>
__global__ __launch_bounds__(512, 1) void k_recur_f(const u8* __restrict__ X8,
                                                    const u8* __restrict__ Wi8,
                                                    const u16* __restrict__ Whh,
                                                    const float* __restrict__ bias_f,
                                                    const float* __restrict__ bias_b,
                                                    void* __restrict__ outp) {
  int dir = blockIdx.y;
  int s0 = blockIdx.x << 4;                 // 16 sequences per block
  int t = threadIdx.x, lane = t & 63, w = t >> 6;  // 8 waves
  int laneg = lane & 15, lk = lane >> 4;
  const u16* Wd = Whh + dir * 65536;
  const u8* Wi = Wi8 + dir * 131072;
  const float* bia = dir ? bias_b : bias_f;
  int hc = w << 4;
  // Whh B-fragments, bf16 (K=128)
  s8v bfr[4][4];
#pragma unroll
  for (int g = 0; g < 4; ++g)
#pragma unroll
    for (int kk = 0; kk < 4; ++kk)
      bfr[g][kk] = *(const s8v*)(Wd + (g * 128 + hc + laneg) * 128 + kk * 32 + lk * 8);
  // Wih B-fragments, fp8 (K=256): 8 bytes per frag -> 64 VGPR total
  long long ifr[4][8];
#pragma unroll
  for (int g = 0; g < 4; ++g)
#pragma unroll
    for (int kk = 0; kk < 8; ++kk)
      ifr[g][kk] = *(const long long*)(Wi + (g * 128 + hc + laneg) * 256 + kk * 32 + lk * 8);
  float bval[4];
#pragma unroll
  for (int g = 0; g < 4; ++g)
    bval[g] = bia[g * 128 + hc + laneg] * ((g == 2) ? GS_G : GS_IFO);

  __shared__ __align__(16) u16 hb[2][16][136];
  __shared__ __align__(16) u8 xb[3][16][256];   // fp8 x tiles, 12 KB
  for (int i = t; i < 2 * 16 * 136; i += 512) ((u16*)hb)[i] = 0;

  float cs[4] = {0.f, 0.f, 0.f, 0.f};
  int tc0 = dir ? 63 : 0;
  int dstep = dir ? -1 : 1;
  // fp8 staging: waves 0-3, 4 rows each (1024B per gl_lds instr, linear dest)
  int srw = (w << 2) + (lane >> 4);         // 0..15 for w<4
  int c16 = lane & 15;
  const u8* xsrc = X8 + (s0 + srw) * 16384 + ((c16 ^ (srw & 7)) << 4);
  // h-store lane mapping (coalesced rows)
  int srow = (w << 1) + (lane >> 5);        // 0..15
  int schunk = lane & 31;                   // 0..31
  int rowb = ((s0 >> 6) << 12) + (s0 & 63);
  // prologue: stage x(t0)->xb[0], x(t0+1)->xb[1]; full drain once.
  if (w < 4) {
    gl_lds16(xsrc + tc0 * 256, &xb[0][w << 2][0]);
    gl_lds16(xsrc + ((tc0 + dstep) & 63) * 256, &xb[1][w << 2][0]);
  }
  __syncthreads();
  int cur = 0;
  for (int st = 0; st < 64; ++st) {
    int tc = tc0 + st * dstep;
    // 1. store h of previous step (reads hb[cur]; this step's writes go to hb[cur^1])
    if (st) {
      int pr = tc - dstep;
      uint2 hv = *(const uint2*)&hb[cur][srow][schunk << 2];
      if (OUT8) {
        float f0 = b2f((u16)(hv.x & 0xffff)), f1 = b2f((u16)(hv.x >> 16));
        float f2 = b2f((u16)(hv.y & 0xffff)), f3 = b2f((u16)(hv.y >> 16));
        u32 p = pkfp8<false>(f0, f1, 0);
        p = pkfp8<true>(f2, f3, p);
        *(u32*)((u8*)outp + (rowb + pr * 64 + srow) * 256 + (dir << 7) + (schunk << 2)) = p;
      } else {
        *(uint2*)((u16*)outp + (rowb + pr * 64 + srow) * 256 + (dir << 7) + (schunk << 2)) = hv;
      }
    }
    // 2. prefetch x(t+2) into xb[(st+2)%3] (last read at step st-1; race-free post-barrier)
    if (w < 4 && st < 62) {
      int tn = tc0 + (st + 2) * dstep;
      gl_lds16(xsrc + tn * 256, &xb[(st + 2) % 3][w << 2][0]);
    }
    // 3. acc = bias + Wih.x_t (fp8 MFMA) + Whh.h (bf16 MFMA)
    f4v acc[4];
#pragma unroll
    for (int g = 0; g < 4; ++g)
      acc[g] = (f4v){bval[g], bval[g], bval[g], bval[g]};
    {
      const u8* xrow = &xb[st % 3][laneg][0];
      long long xf[8];
#pragma unroll
      for (int kk = 0; kk < 8; ++kk)
        xf[kk] = *(const long long*)&xrow[((((kk << 1) + (lk >> 1)) ^ (laneg & 7)) << 4) + ((lk & 1) << 3)];
#pragma unroll
      for (int g = 0; g < 4; ++g)
#pragma unroll
        for (int kk = 0; kk < 8; ++kk)
          acc[g] = __builtin_amdgcn_mfma_f32_16x16x32_fp8_fp8(xf[kk], ifr[g][kk], acc[g], 0, 0, 0);
    }
    {
      s8v afr[4];
#pragma unroll
      for (int kk = 0; kk < 4; ++kk)
        afr[kk] = *(const s8v*)&hb[cur][laneg][kk * 32 + lk * 8];
#pragma unroll
      for (int g = 0; g < 4; ++g)
#pragma unroll
        for (int kk = 0; kk < 4; ++kk)
          acc[g] = __builtin_amdgcn_mfma_f32_16x16x32_bf16(afr[kk], bfr[g][kk], acc[g], 0, 0, 0);
    }
    // 4. gates
    int nxt = cur ^ 1;
#pragma unroll
    for (int j = 0; j < 4; ++j) {
      float iv = rcpf(1.0f + ex2(-acc[0][j]));
      float fv = rcpf(1.0f + ex2(-acc[1][j]));
      float gv = 1.0f - 2.0f * rcpf(1.0f + ex2(acc[2][j]));
      float ov = rcpf(1.0f + ex2(-acc[3][j]));
      float c = fv * cs[j] + iv * gv;
      cs[j] = c;
      float th = 1.0f - 2.0f * rcpf(1.0f + ex2(c * GS_G));
      hb[nxt][lk * 4 + j][hc + laneg] = f2b(ov * th);
    }
    // 5. LDS-only barrier (global write-acks and young prefetches stay in flight)
    asm volatile("s_waitcnt lgkmcnt(0)" ::: "memory");
    __builtin_amdgcn_s_barrier();
    cur = nxt;
  }
  // final h store
  {
    int pr = tc0 + 63 * dstep;
    uint2 hv = *(const uint2*)&hb[cur][srow][schunk << 2];
    if (OUT8) {
      float f0 = b2f((u16)(hv.x & 0xffff)), f1 = b2f((u16)(hv.x >> 16));
      float f2 = b2f((u16)(hv.y & 0xffff)), f3 = b2f((u16)(hv.y >> 16));
      u32 p = pkfp8<false>(f0, f1, 0);
      p = pkfp8<true>(f2, f3, p);
      *(u32*)((u8*)outp + (rowb + pr * 64 + srow) * 256 + (dir << 7) + (schunk << 2)) = p;
    } else {
      *(uint2*)((u16*)outp + (rowb + pr * 64 + srow) * 256 + (dir << 7) + (schunk << 2)) = hv;
    }
  }
}

// ------- fused attention + final: att = (qavg/Z) . evf ; out = in*(1+al*sig(att)) -------
__global__ __launch_bounds__(256) void k_attfin(const u16* __restrict__ VF,
                                                const float* __restrict__ qavg,
                                                const float* __restrict__ Z,
                                                const float* __restrict__ in,
                                                const float* __restrict__ alpha,
                                                float* __restrict__ out) {
  int bx = blockIdx.x;
  int b = bx >> 6;
  int sp0 = (bx & 63) << 6;
  int t = threadIdx.x, lane = t & 63, wid = t >> 6;
  __shared__ __align__(16) float lwo[256];
  __shared__ float fac[64];
  lwo[t] = qavg[b * 256 + t] / Z[b * 256 + t];
  __syncthreads();
  float4 wo = *(const float4*)&lwo[lane * 4];
  int rowbase = b * 4096 + sp0;
#pragma unroll 4
  for (int i = 0; i < 16; ++i) {
    int r = wid * 16 + i;
    uint2 v = *(const uint2*)&VF[(rowbase + r) * 256 + lane * 4];
    float x0 = b2f((u16)(v.x & 0xffff)), x1 = b2f((u16)(v.x >> 16));
    float x2 = b2f((u16)(v.y & 0xffff)), x3 = b2f((u16)(v.y >> 16));
    float p = wo.x * x0 + wo.y * x1 + wo.z * x2 + wo.w * x3;
#pragma unroll
    for (int off = 32; off; off >>= 1) p += __shfl_xor(p, off);
    if (lane == 0) fac[r] = p;
  }
  __syncthreads();
  float al = alpha[0];
  if (t < 64) fac[t] = 1.0f + al * sigf(fac[t]);
  __syncthreads();
  int sp = t & 63;
  float f = fac[sp];
  const float* ip = in + (long)b * 1048576 + sp0 + sp;
  float* op = out + (long)b * 1048576 + sp0 + sp;
  int c0 = t >> 6;
#pragma unroll 8
  for (int c = c0; c < 256; c += 4) {
    op[c * 4096] = ip[c * 4096] * f;
  }
}

extern "C" void kernel_launch(void* const* d_in, const int* in_sizes, int n_in,
                              void* d_out, int out_size, void* d_ws, size_t ws_size,
                              hipStream_t stream) {
  const float* input   = (const float*)d_in[0];
  const float* h_Wih_f = (const float*)d_in[1];
  const float* h_Whh_f = (const float*)d_in[2];
  const float* h_b_f   = (const float*)d_in[3];
  const float* h_Wih_b = (const float*)d_in[4];
  const float* h_Whh_b = (const float*)d_in[5];
  const float* h_b_b   = (const float*)d_in[6];
  const float* v_Wih_f = (const float*)d_in[7];
  const float* v_Whh_f = (const float*)d_in[8];
  const float* v_b_f   = (const float*)d_in[9];
  const float* v_Wih_b = (const float*)d_in[10];
  const float* v_Whh_b = (const float*)d_in[11];
  const float* v_b_b   = (const float*)d_in[12];
  const float* Wr      = (const float*)d_in[13];
  const float* Wl      = (const float*)d_in[14];
  const float* alphap  = (const float*)d_in[15];

  char* ws = (char*)d_ws;
  u8*  Ah8   = (u8*)(ws + 0);              // 16,777,216 B fp8 x (stage1); later Ar bf16 33.5MB
  u16* VF    = (u16*)(ws + 33554432);      // 33,554,432 B
  u8*  Wh8   = (u8*)(ws + 67108864);       // 262,144 fp8 [2][512][256]
  u8*  Wv8   = (u8*)(ws + 67371008);       // 262,144
  u16* WhhH  = (u16*)(ws + 67633152);      // 262,144 bf16 [2][512][128]
  u16* WhhV  = (u16*)(ws + 67895296);      // 262,144
  u16* Wrb   = (u16*)(ws + 68157440);      // 131,072 bf16 [256][256]
  float* meansum = (float*)(ws + 68288512);
  float* qavg    = (float*)(ws + 68304896);
  float* pZ      = (float*)(ws + 68321280);
  u8*  Av8 = (u8*)d_out;                   // stage1 fp8 output (16.7MB, dead before attfin)
  u16* Ar  = (u16*)(ws + 0);               // stage2 bf16 output (33.5MB over dead Ah8)

  (void)hipMemsetAsync(meansum, 0, 16 * 256 * 4, stream);
  (void)hipMemsetAsync(pZ, 0, 16 * 256 * 4, stream);

  CvtArgs ca;
  ca.src[0] = h_Wih_f; ca.dst[0] = Wh8;           ca.n4[0] = 32768; ca.scl[0] = 1; ca.sh[0] = 6; ca.to8[0] = 1;
  ca.src[1] = h_Wih_b; ca.dst[1] = Wh8 + 131072;  ca.n4[1] = 32768; ca.scl[1] = 1; ca.sh[1] = 6; ca.to8[1] = 1;
  ca.src[2] = v_Wih_f; ca.dst[2] = Wv8;           ca.n4[2] = 32768; ca.scl[2] = 1; ca.sh[2] = 6; ca.to8[2] = 1;
  ca.src[3] = v_Wih_b; ca.dst[3] = Wv8 + 131072;  ca.n4[3] = 32768; ca.scl[3] = 1; ca.sh[3] = 6; ca.to8[3] = 1;
  ca.src[4] = h_Whh_f; ca.dst[4] = WhhH;          ca.n4[4] = 16384; ca.scl[4] = 1; ca.sh[4] = 5; ca.to8[4] = 0;
  ca.src[5] = h_Whh_b; ca.dst[5] = WhhH + 65536;  ca.n4[5] = 16384; ca.scl[5] = 1; ca.sh[5] = 5; ca.to8[5] = 0;
  ca.src[6] = v_Whh_f; ca.dst[6] = WhhV;          ca.n4[6] = 16384; ca.scl[6] = 1; ca.sh[6] = 5; ca.to8[6] = 0;
  ca.src[7] = v_Whh_b; ca.dst[7] = WhhV + 65536;  ca.n4[7] = 16384; ca.scl[7] = 1; ca.sh[7] = 5; ca.to8[7] = 0;
  ca.src[8] = Wr;      ca.dst[8] = Wrb;           ca.n4[8] = 16384; ca.scl[8] = 2; ca.sh[8] = 6; ca.to8[8] = 0;
  k_cvt<<<dim3(128, 9), 256, 0, stream>>>(ca);

  k_tin<<<dim3(4, 64, 16), 256, 0, stream>>>(input, Ah8, meansum);
  k_qavg<<<16, 256, 0, stream>>>(meansum, Wl, qavg);

  k_recur_f<true><<<dim3(64, 2), 512, 0, stream>>>(Ah8, Wh8, WhhH, h_b_f, h_b_b, (void*)Av8);
  k_recur_f<false><<<dim3(64, 2), 512, 0, stream>>>(Av8, Wv8, WhhV, v_b_f, v_b_b, (void*)Ar);
  k_gemm2<<<1024, 256, 0, stream>>>(Ar, Wrb, VF, 256, 2, pZ);

  k_attfin<<<1024, 256, 0, stream>>>(VF, qavg, pZ, input, alphap, (float*)d_out);
}

// Round 14
// 315.615 us; speedup vs baseline: 2.1243x; 1.0816x over previous
//
#include <hip/hip_runtime.h>
#include <hip/hip_bf16.h>

typedef unsigned short u16;
typedef unsigned int u32;
typedef unsigned char u8;
typedef long long ll8;                                   // 8 x fp8 operand
typedef __attribute__((ext_vector_type(8))) short s8v;   // 8 x bf16
typedef __attribute__((ext_vector_type(4))) float f4v;   // mfma acc

__device__ __forceinline__ float b2f(u16 u) {
  union { u32 i; float f; } v; v.i = ((u32)u) << 16; return v.f;
}
__device__ __forceinline__ u16 f2b(float f) {
  union { float f; u32 i; } v; v.f = f;
  u32 r = v.i + 0x7FFFu + ((v.i >> 16) & 1u);
  return (u16)(r >> 16);
}
__device__ __forceinline__ float rcpf(float x) { return __builtin_amdgcn_rcpf(x); }
__device__ __forceinline__ float ex2(float x) {
#if __has_builtin(__builtin_amdgcn_exp2f)
  return __builtin_amdgcn_exp2f(x);
#else
  return exp2f(x);
#endif
}
__device__ __forceinline__ float sigf(float x) { return rcpf(1.0f + __expf(-x)); }
// pack 2 floats -> 2 fp8 e4m3 bytes into low/high 16b word of old (HI immediate)
template<bool HI>
__device__ __forceinline__ u32 pkfp8(float a, float b, u32 old) {
  return (u32)__builtin_amdgcn_cvt_pk_fp8_f32(a, b, (int)old, HI);
}
__device__ __forceinline__ u8 f2f8(float x) { return (u8)(pkfp8<false>(x, x, 0) & 0xffu); }
// fp8 e4m3 byte (selected from u32) -> f32
template<int S>
__device__ __forceinline__ float f8tof(u32 v) {
#if __has_builtin(__builtin_amdgcn_cvt_f32_fp8)
  return __builtin_amdgcn_cvt_f32_fp8((int)v, S);
#else
  u8 b = (u8)(v >> (8 * S));
  u32 s = (b >> 7) & 1u, e = (b >> 3) & 15u, m = b & 7u;
  union { u32 i; float f; } r;
  if (e) r.i = (s << 31) | ((e + 120u) << 23) | (m << 20);
  else { r.f = (float)m * 0.001953125f; r.i |= s << 31; }
  return r.f;
#endif
}

#define GS_IFO 1.4426950408889634f
#define GS_G   2.8853900817779268f

__device__ __forceinline__ void gl_lds16(const void* g, void* l) {
  __builtin_amdgcn_global_load_lds(
      (const __attribute__((address_space(1))) u32*)g,
      (__attribute__((address_space(3))) u32*)l, 16, 0, 0);
}

// ---------------- weight conversion fp32 -> fp8 (all weights) ----------------
// scl: 1 gate-pattern (exp2 domain), 2 uniform log2e. sh: log2(float4s/row).
struct CvtArgs {
  const float* src[9];
  u8* dst[9];
  int n4[9];
  int scl[9];
  int sh[9];
};
__global__ __launch_bounds__(256) void k_cvt(CvtArgs a) {
  int seg = blockIdx.y;
  int i = blockIdx.x * 256 + threadIdx.x;
  if (i >= a.n4[seg]) return;
  float4 v = ((const float4*)a.src[seg])[i];
  float s;
  if (a.scl[seg] == 2) {
    s = GS_IFO;
  } else {
    int r = i >> a.sh[seg];
    s = (((r >> 7) & 3) == 2) ? GS_G : GS_IFO;
  }
  v.x *= s; v.y *= s; v.z *= s; v.w *= s;
  u32 p = pkfp8<false>(v.x, v.y, 0);
  p = pkfp8<true>(v.z, v.w, p);
  ((u32*)a.dst[seg])[i] = p;
}

// ------- transpose input [B,C,H,W] -> fp8 x [(b,w,h)][c]; also channel sums -------
__global__ __launch_bounds__(256) void k_tin(const float* __restrict__ in,
                                             u8* __restrict__ A8,
                                             float* __restrict__ meansum) {
  int b = blockIdx.z, h = blockIdx.y, c0 = blockIdx.x * 64;
  int t = threadIdx.x, lane = t & 63, q = t >> 6;
  __shared__ u8 lT[64][68];
  const float* src = in + ((b * 256 + c0) * 64 + h) * 64;
#pragma unroll 4
  for (int i = 0; i < 16; ++i) {
    int cl = q * 16 + i;
    float v = src[cl * 4096 + lane];
    lT[cl][lane] = f2f8(v);
    float s = v;
#pragma unroll
    for (int off = 32; off; off >>= 1) s += __shfl_xor(s, off);
    if (lane == 0) atomicAdd(&meansum[b * 256 + c0 + cl], s);
  }
  __syncthreads();
  u8* dst = A8 + (b * 4096 + h) * 256 + c0;
#pragma unroll 4
  for (int i = 0; i < 16; ++i) {
    int w = q * 16 + i;
    dst[w * 16384 + lane] = lT[lane][w];
  }
}

// ------- q_avg[b][o] = softmax_o( Wl[o,:] . mean_c ) -------
__global__ __launch_bounds__(256) void k_qavg(const float* __restrict__ meansum,
                                              const float* __restrict__ Wl,
                                              float* __restrict__ qavg) {
  int b = blockIdx.x, t = threadIdx.x;
  __shared__ float mean[256];
  __shared__ float red[256];
  mean[t] = meansum[b * 256 + t] * (1.0f / 4096.0f);
  __syncthreads();
  const float* wr = Wl + t * 256;
  float acc = 0.0f;
  for (int c = 0; c < 256; ++c) acc = fmaf(wr[c], mean[c], acc);
  red[t] = acc; __syncthreads();
  for (int s = 128; s; s >>= 1) { if (t < s) red[t] = fmaxf(red[t], red[t + s]); __syncthreads(); }
  float mx = red[0]; __syncthreads();
  float e = __expf(acc - mx);
  red[t] = e; __syncthreads();
  for (int s = 128; s; s >>= 1) { if (t < s) red[t] += red[t + s]; __syncthreads(); }
  qavg[b * 256 + t] = e / red[0];
}

// ------- 128x128 fp8 GEMM, full-K resident (Wr path): VF=fp8(exp2(A.W)), Zsum atomics ----
__global__ __launch_bounds__(256, 2) void k_gemm8(const u8* __restrict__ A,
                                                  const u8* __restrict__ W,
                                                  u8* __restrict__ out,
                                                  float* __restrict__ Zsum) {
  int nwg = gridDim.x;
  int q = nwg >> 3;
  int bid = blockIdx.x;
  int swz = (bid & 7) * q + (bid >> 3);
  int mt = swz >> 1, nt = swz & 1;          // NT = 2
  int mb = mt << 7, nb = nt << 7;
  int t = threadIdx.x, lane = t & 63, wid = t >> 6;
  int laneg = lane & 15, lk = lane >> 4;
  __shared__ __align__(16) u8 lA[128][256];
  __shared__ __align__(16) u8 lW[128][256];
  {
    int rl = lane >> 4;                     // 0..3 row within 4-row round
    int unit = lane & 15;
#pragma unroll
    for (int i = 0; i < 8; ++i) {
      int rb4 = ((wid << 3) + i) << 2;      // 4-row block base
      int r = rb4 + rl;
      int usA = unit ^ (r & 7);
      gl_lds16(A + (mb + r) * 256 + (usA << 4), &lA[rb4][0]);
      gl_lds16(W + (nb + r) * 256 + (usA << 4), &lW[rb4][0]);
    }
  }
  __syncthreads();
  f4v acc[4][4] = {};
  int wm = wid >> 1, wn = wid & 1;
#pragma unroll
  for (int kk = 0; kk < 8; ++kk) {
    ll8 af[4], bf[4];
#pragma unroll
    for (int m = 0; m < 4; ++m) {
      int r = (wm << 6) + (m << 4) + laneg;
      int us = ((kk << 1) + (lk >> 1)) ^ (r & 7);
      af[m] = *(const ll8*)&lA[r][(us << 4) + ((lk & 1) << 3)];
    }
#pragma unroll
    for (int n = 0; n < 4; ++n) {
      int r = (wn << 6) + (n << 4) + laneg;
      int us = ((kk << 1) + (lk >> 1)) ^ (r & 7);
      bf[n] = *(const ll8*)&lW[r][(us << 4) + ((lk & 1) << 3)];
    }
#pragma unroll
    for (int m = 0; m < 4; ++m)
#pragma unroll
      for (int n = 0; n < 4; ++n)
        acc[m][n] = __builtin_amdgcn_mfma_f32_16x16x32_fp8_fp8(af[m], bf[n], acc[m][n], 0, 0, 0);
  }
#pragma unroll
  for (int n = 0; n < 4; ++n) {
    int col = nb + (wn << 6) + (n << 4) + laneg;
    float csum = 0.f;
#pragma unroll
    for (int m = 0; m < 4; ++m) {
      int row0 = mb + (wm << 6) + (m << 4) + (lk << 2);
#pragma unroll
      for (int j = 0; j < 4; ++j) {
        float e = ex2(acc[m][n][j]);
        csum += e;
        out[(row0 + j) * 256 + col] = f2f8(e);
      }
    }
    csum += __shfl_xor(csum, 16);
    csum += __shfl_xor(csum, 32);
    if (lk == 0) atomicAdd(&Zsum[((mb >> 12) << 8) + col], csum);
  }
}

// ------- FUSED biLSTM v6: full fp8 datapath (x, Wih, h, Whh in e4m3), f32 gates.
//         R9 step structure: 3-buffer distance-2 prefetch, lgkm-only barrier. -------
// X8: fp8 [seq*64+t][256]; Wi8: fp8 [2][512][256]; Wh8d: fp8 [2][512][128]; out fp8.
__global__ __launch_bounds__(512, 1) void k_recur_f(const u8* __restrict__ X8,
                                                    const u8* __restrict__ Wi8,
                                                    const u8* __restrict__ Wh8d,
                                                    const float* __restrict__ bias_f,
                                                    const float* __restrict__ bias_b,
                                                    u8* __restrict__ outb) {
  int dir = blockIdx.y;
  int s0 = blockIdx.x << 4;                 // 16 sequences per block
  int t = threadIdx.x, lane = t & 63, w = t >> 6;  // 8 waves
  int laneg = lane & 15, lk = lane >> 4;
  const u8* Wd = Wh8d + dir * 65536;
  const u8* Wi = Wi8 + dir * 131072;
  const float* bia = dir ? bias_b : bias_f;
  int hc = w << 4;
  // Whh B-fragments, fp8 (K=128): 32 VGPR
  ll8 bfr[4][4];
#pragma unroll
  for (int g = 0; g < 4; ++g)
#pragma unroll
    for (int kk = 0; kk < 4; ++kk)
      bfr[g][kk] = *(const ll8*)(Wd + (g * 128 + hc + laneg) * 128 + kk * 32 + lk * 8);
  // Wih B-fragments, fp8 (K=256): 64 VGPR
  ll8 ifr[4][8];
#pragma unroll
  for (int g = 0; g < 4; ++g)
#pragma unroll
    for (int kk = 0; kk < 8; ++kk)
      ifr[g][kk] = *(const ll8*)(Wi + (g * 128 + hc + laneg) * 256 + kk * 32 + lk * 8);
  float bval[4];
#pragma unroll
  for (int g = 0; g < 4; ++g)
    bval[g] = bia[g * 128 + hc + laneg] * ((g == 2) ? GS_G : GS_IFO);

  __shared__ __align__(16) u8 hb[2][16][144];   // fp8 h, pad 144 -> conflict-floor b64 reads
  __shared__ __align__(16) u8 xb[3][16][256];   // fp8 x tiles, 12 KB
  for (int i = t; i < 2 * 16 * 144; i += 512) ((u8*)hb)[i] = 0;

  float cs[4] = {0.f, 0.f, 0.f, 0.f};
  int tc0 = dir ? 63 : 0;
  int dstep = dir ? -1 : 1;
  // fp8 x staging: waves 0-3, 4 rows each (1024B per gl_lds instr, linear dest)
  int srw = (w << 2) + (lane >> 4);         // 0..15 for w<4
  int c16 = lane & 15;
  const u8* xsrc = X8 + (s0 + srw) * 16384 + ((c16 ^ (srw & 7)) << 4);
  // h-store lane mapping: 512 threads cover 16 rows x 32 u32-chunks
  int srow = t >> 5;                        // 0..15
  int schunk = t & 31;                      // 0..31
  int rowb = ((s0 >> 6) << 12) + (s0 & 63);
  // prologue: stage x(t0)->xb[0], x(t0+1)->xb[1]; full drain once.
  if (w < 4) {
    gl_lds16(xsrc + tc0 * 256, &xb[0][w << 2][0]);
    gl_lds16(xsrc + ((tc0 + dstep) & 63) * 256, &xb[1][w << 2][0]);
  }
  __syncthreads();
  int cur = 0;
  for (int st = 0; st < 64; ++st) {
    int tc = tc0 + st * dstep;
    // 1. store h of previous step (reads hb[cur]; this step's writes go to hb[cur^1])
    if (st) {
      int pr = tc - dstep;
      u32 hv = *(const u32*)&hb[cur][srow][schunk << 2];
      *(u32*)(outb + (rowb + pr * 64 + srow) * 256 + (dir << 7) + (schunk << 2)) = hv;
    }
    // 2. prefetch x(t+2) into xb[(st+2)%3]
    if (w < 4 && st < 62) {
      int tn = tc0 + (st + 2) * dstep;
      gl_lds16(xsrc + tn * 256, &xb[(st + 2) % 3][w << 2][0]);
    }
    // 3. acc = bias + Wih.x_t + Whh.h (all fp8 MFMA)
    f4v acc[4];
#pragma unroll
    for (int g = 0; g < 4; ++g)
      acc[g] = (f4v){bval[g], bval[g], bval[g], bval[g]};
    {
      const u8* xrow = &xb[st % 3][laneg][0];
      ll8 xf[8];
#pragma unroll
      for (int kk = 0; kk < 8; ++kk)
        xf[kk] = *(const ll8*)&xrow[((((kk << 1) + (lk >> 1)) ^ (laneg & 7)) << 4) + ((lk & 1) << 3)];
#pragma unroll
      for (int g = 0; g < 4; ++g)
#pragma unroll
        for (int kk = 0; kk < 8; ++kk)
          acc[g] = __builtin_amdgcn_mfma_f32_16x16x32_fp8_fp8(xf[kk], ifr[g][kk], acc[g], 0, 0, 0);
    }
    {
      ll8 afr[4];
#pragma unroll
      for (int kk = 0; kk < 4; ++kk)
        afr[kk] = *(const ll8*)&hb[cur][laneg][kk * 32 + lk * 8];
#pragma unroll
      for (int g = 0; g < 4; ++g)
#pragma unroll
        for (int kk = 0; kk < 4; ++kk)
          acc[g] = __builtin_amdgcn_mfma_f32_16x16x32_fp8_fp8(afr[kk], bfr[g][kk], acc[g], 0, 0, 0);
    }
    // 4. gates (f32), h -> fp8 LDS
    int nxt = cur ^ 1;
#pragma unroll
    for (int j = 0; j < 4; ++j) {
      float iv = rcpf(1.0f + ex2(-acc[0][j]));
      float fv = rcpf(1.0f + ex2(-acc[1][j]));
      float gv = 1.0f - 2.0f * rcpf(1.0f + ex2(acc[2][j]));
      float ov = rcpf(1.0f + ex2(-acc[3][j]));
      float c = fv * cs[j] + iv * gv;
      cs[j] = c;
      float th = 1.0f - 2.0f * rcpf(1.0f + ex2(c * GS_G));
      hb[nxt][(lk << 2) + j][hc + laneg] = f2f8(ov * th);
    }
    // 5. LDS-only barrier (global write-acks and young prefetches stay in flight)
    asm volatile("s_waitcnt lgkmcnt(0)" ::: "memory");
    __builtin_amdgcn_s_barrier();
    cur = nxt;
  }
  // final h store
  {
    int pr = tc0 + 63 * dstep;
    u32 hv = *(const u32*)&hb[cur][srow][schunk << 2];
    *(u32*)(outb + (rowb + pr * 64 + srow) * 256 + (dir << 7) + (schunk << 2)) = hv;
  }
}

// ------- fused attention + final: att = (qavg/Z) . evf(fp8) ; out = in*(1+al*sig(att)) ----
__global__ __launch_bounds__(256) void k_attfin(const u8* __restrict__ VF8,
                                                const float* __restrict__ qavg,
                                                const float* __restrict__ Z,
                                                const float* __restrict__ in,
                                                const float* __restrict__ alpha,
                                                float* __restrict__ out) {
  int bx = blockIdx.x;
  int b = bx >> 6;
  int sp0 = (bx & 63) << 6;
  int t = threadIdx.x, lane = t & 63, wid = t >> 6;
  __shared__ __align__(16) float lwo[256];
  __shared__ float fac[64];
  lwo[t] = qavg[b * 256 + t] / Z[b * 256 + t];
  __syncthreads();
  float4 wo = *(const float4*)&lwo[lane * 4];
  int rowbase = b * 4096 + sp0;
#pragma unroll 4
  for (int i = 0; i < 16; ++i) {
    int r = wid * 16 + i;
    u32 v = *(const u32*)&VF8[(rowbase + r) * 256 + lane * 4];
    float p = wo.x * f8tof<0>(v) + wo.y * f8tof<1>(v) +
              wo.z * f8tof<2>(v) + wo.w * f8tof<3>(v);
#pragma unroll
    for (int off = 32; off; off >>= 1) p += __shfl_xor(p, off);
    if (lane == 0) fac[r] = p;
  }
  __syncthreads();
  float al = alpha[0];
  if (t < 64) fac[t] = 1.0f + al * sigf(fac[t]);
  __syncthreads();
  int sp = t & 63;
  float f = fac[sp];
  const float* ip = in + (long)b * 1048576 + sp0 + sp;
  float* op = out + (long)b * 1048576 + sp0 + sp;
  int c0 = t >> 6;
#pragma unroll 8
  for (int c = c0; c < 256; c += 4) {
    op[c * 4096] = ip[c * 4096] * f;
  }
}

extern "C" void kernel_launch(void* const* d_in, const int* in_sizes, int n_in,
                              void* d_out, int out_size, void* d_ws, size_t ws_size,
                              hipStream_t stream) {
  const float* input   = (const float*)d_in[0];
  const float* h_Wih_f = (const float*)d_in[1];
  const float* h_Whh_f = (const float*)d_in[2];
  const float* h_b_f   = (const float*)d_in[3];
  const float* h_Wih_b = (const float*)d_in[4];
  const float* h_Whh_b = (const float*)d_in[5];
  const float* h_b_b   = (const float*)d_in[6];
  const float* v_Wih_f = (const float*)d_in[7];
  const float* v_Whh_f = (const float*)d_in[8];
  const float* v_b_f   = (const float*)d_in[9];
  const float* v_Wih_b = (const float*)d_in[10];
  const float* v_Whh_b = (const float*)d_in[11];
  const float* v_b_b   = (const float*)d_in[12];
  const float* Wr      = (const float*)d_in[13];
  const float* Wl      = (const float*)d_in[14];
  const float* alphap  = (const float*)d_in[15];

  char* ws = (char*)d_ws;
  u8*  Ah8   = (u8*)(ws + 0);              // 16,777,216 B fp8 x (stage1); later Ar8
  u8*  VF8   = (u8*)(ws + 33554432);       // 16,777,216 B fp8 evf
  u8*  Wh8   = (u8*)(ws + 67108864);       // 262,144 fp8 [2][512][256]
  u8*  Wv8   = (u8*)(ws + 67371008);       // 262,144
  u8*  WhhH8 = (u8*)(ws + 67633152);       // 131,072 fp8 [2][512][128]
  u8*  WhhV8 = (u8*)(ws + 67764224);       // 131,072
  u8*  Wrb8  = (u8*)(ws + 67895296);       // 65,536 fp8 [256][256]
  float* meansum = (float*)(ws + 67960832);  // 16 KB
  float* qavg    = (float*)(ws + 67977216);  // 16 KB
  float* pZ      = (float*)(ws + 67993600);  // 16 KB
  u8*  Av8 = (u8*)d_out;                   // stage1 fp8 output (16.7MB, dead before attfin)
  u8*  Ar8 = Ah8;                          // stage2 fp8 output over dead Ah8

  (void)hipMemsetAsync(meansum, 0, 3 * 16384, stream);  // meansum + qavg + pZ

  CvtArgs ca;
  ca.src[0] = h_Wih_f; ca.dst[0] = Wh8;           ca.n4[0] = 32768; ca.scl[0] = 1; ca.sh[0] = 6;
  ca.src[1] = h_Wih_b; ca.dst[1] = Wh8 + 131072;  ca.n4[1] = 32768; ca.scl[1] = 1; ca.sh[1] = 6;
  ca.src[2] = v_Wih_f; ca.dst[2] = Wv8;           ca.n4[2] = 32768; ca.scl[2] = 1; ca.sh[2] = 6;
  ca.src[3] = v_Wih_b; ca.dst[3] = Wv8 + 131072;  ca.n4[3] = 32768; ca.scl[3] = 1; ca.sh[3] = 6;
  ca.src[4] = h_Whh_f; ca.dst[4] = WhhH8;         ca.n4[4] = 16384; ca.scl[4] = 1; ca.sh[4] = 5;
  ca.src[5] = h_Whh_b; ca.dst[5] = WhhH8 + 65536; ca.n4[5] = 16384; ca.scl[5] = 1; ca.sh[5] = 5;
  ca.src[6] = v_Whh_f; ca.dst[6] = WhhV8;         ca.n4[6] = 16384; ca.scl[6] = 1; ca.sh[6] = 5;
  ca.src[7] = v_Whh_b; ca.dst[7] = WhhV8 + 65536; ca.n4[7] = 16384; ca.scl[7] = 1; ca.sh[7] = 5;
  ca.src[8] = Wr;      ca.dst[8] = Wrb8;          ca.n4[8] = 16384; ca.scl[8] = 2; ca.sh[8] = 6;
  k_cvt<<<dim3(128, 9), 256, 0, stream>>>(ca);

  k_tin<<<dim3(4, 64, 16), 256, 0, stream>>>(input, Ah8, meansum);
  k_qavg<<<16, 256, 0, stream>>>(meansum, Wl, qavg);

  k_recur_f<<<dim3(64, 2), 512, 0, stream>>>(Ah8, Wh8, WhhH8, h_b_f, h_b_b, Av8);
  k_recur_f<<<dim3(64, 2), 512, 0, stream>>>(Av8, Wv8, WhhV8, v_b_f, v_b_b, Ar8);
  k_gemm8<<<1024, 256, 0, stream>>>(Ar8, Wrb8, VF8, pZ);

  k_attfin<<<1024, 256, 0, stream>>>(VF8, qavg, pZ, input, alphap, (float*)d_out);
}

// Round 15
// 307.246 us; speedup vs baseline: 2.1822x; 1.0272x over previous
//
#include <hip/hip_runtime.h>
#include <hip/hip_bf16.h>

typedef unsigned short u16;
typedef unsigned int u32;
typedef unsigned char u8;
typedef long long ll8;                                   // 8 x fp8 operand
typedef __attribute__((ext_vector_type(4))) float f4v;   // mfma acc

__device__ __forceinline__ float rcpf(float x) { return __builtin_amdgcn_rcpf(x); }
__device__ __forceinline__ float ex2(float x) {
#if __has_builtin(__builtin_amdgcn_exp2f)
  return __builtin_amdgcn_exp2f(x);
#else
  return exp2f(x);
#endif
}
__device__ __forceinline__ float sigf(float x) { return rcpf(1.0f + __expf(-x)); }
// pack 2 floats -> 2 fp8 e4m3 bytes into low/high 16b word of old (HI immediate)
template<bool HI>
__device__ __forceinline__ u32 pkfp8(float a, float b, u32 old) {
  return (u32)__builtin_amdgcn_cvt_pk_fp8_f32(a, b, (int)old, HI);
}
__device__ __forceinline__ u8 f2f8(float x) { return (u8)(pkfp8<false>(x, x, 0) & 0xffu); }
// fp8 e4m3 byte (selected from u32) -> f32
template<int S>
__device__ __forceinline__ float f8tof(u32 v) {
#if __has_builtin(__builtin_amdgcn_cvt_f32_fp8)
  return __builtin_amdgcn_cvt_f32_fp8((int)v, S);
#else
  u8 b = (u8)(v >> (8 * S));
  u32 s = (b >> 7) & 1u, e = (b >> 3) & 15u, m = b & 7u;
  union { u32 i; float f; } r;
  if (e) r.i = (s << 31) | ((e + 120u) << 23) | (m << 20);
  else { r.f = (float)m * 0.001953125f; r.i |= s << 31; }
  return r.f;
#endif
}

#define GS_IFO 1.4426950408889634f
#define GS_G   2.8853900817779268f

__device__ __forceinline__ void gl_lds16(const void* g, void* l) {
  __builtin_amdgcn_global_load_lds(
      (const __attribute__((address_space(1))) u32*)g,
      (__attribute__((address_space(3))) u32*)l, 16, 0, 0);
}

// ---------------- weight conversion fp32 -> fp8 (all weights) ----------------
struct CvtArgs {
  const float* src[9];
  u8* dst[9];
  int n4[9];
  int scl[9];
  int sh[9];
};
__global__ __launch_bounds__(256) void k_cvt(CvtArgs a) {
  int seg = blockIdx.y;
  int i = blockIdx.x * 256 + threadIdx.x;
  if (i >= a.n4[seg]) return;
  float4 v = ((const float4*)a.src[seg])[i];
  float s;
  if (a.scl[seg] == 2) {
    s = GS_IFO;
  } else {
    int r = i >> a.sh[seg];
    s = (((r >> 7) & 3) == 2) ? GS_G : GS_IFO;
  }
  v.x *= s; v.y *= s; v.z *= s; v.w *= s;
  u32 p = pkfp8<false>(v.x, v.y, 0);
  p = pkfp8<true>(v.z, v.w, p);
  ((u32*)a.dst[seg])[i] = p;
}

// ------- transpose input [B,C,H,W] -> fp8 x [(b,w,h)][c]; also channel sums -------
__global__ __launch_bounds__(256) void k_tin(const float* __restrict__ in,
                                             u8* __restrict__ A8,
                                             float* __restrict__ meansum) {
  int b = blockIdx.z, h = blockIdx.y, c0 = blockIdx.x * 64;
  int t = threadIdx.x, lane = t & 63, q = t >> 6;
  __shared__ u8 lT[64][68];
  const float* src = in + ((b * 256 + c0) * 64 + h) * 64;
#pragma unroll 4
  for (int i = 0; i < 16; ++i) {
    int cl = q * 16 + i;
    float v = src[cl * 4096 + lane];
    lT[cl][lane] = f2f8(v);
    float s = v;
#pragma unroll
    for (int off = 32; off; off >>= 1) s += __shfl_xor(s, off);
    if (lane == 0) atomicAdd(&meansum[b * 256 + c0 + cl], s);
  }
  __syncthreads();
  u8* dst = A8 + (b * 4096 + h) * 256 + c0;
#pragma unroll 4
  for (int i = 0; i < 16; ++i) {
    int w = q * 16 + i;
    dst[w * 16384 + lane] = lT[lane][w];
  }
}

// ------- q_avg[b][o] = softmax_o( Wl[o,:] . mean_c ) -------
__global__ __launch_bounds__(256) void k_qavg(const float* __restrict__ meansum,
                                              const float* __restrict__ Wl,
                                              float* __restrict__ qavg) {
  int b = blockIdx.x, t = threadIdx.x;
  __shared__ float mean[256];
  __shared__ float red[256];
  mean[t] = meansum[b * 256 + t] * (1.0f / 4096.0f);
  __syncthreads();
  const float* wr = Wl + t * 256;
  float acc = 0.0f;
  for (int c = 0; c < 256; ++c) acc = fmaf(wr[c], mean[c], acc);
  red[t] = acc; __syncthreads();
  for (int s = 128; s; s >>= 1) { if (t < s) red[t] = fmaxf(red[t], red[t + s]); __syncthreads(); }
  float mx = red[0]; __syncthreads();
  float e = __expf(acc - mx);
  red[t] = e; __syncthreads();
  for (int s = 128; s; s >>= 1) { if (t < s) red[t] += red[t + s]; __syncthreads(); }
  qavg[b * 256 + t] = e / red[0];
}

// ------- 128x128 fp8 GEMM, full-K resident (Wr path): VF=fp8(exp2(A.W)), Zsum atomics ----
__global__ __launch_bounds__(256, 2) void k_gemm8(const u8* __restrict__ A,
                                                  const u8* __restrict__ W,
                                                  u8* __restrict__ out,
                                                  float* __restrict__ Zsum) {
  int nwg = gridDim.x;
  int q = nwg >> 3;
  int bid = blockIdx.x;
  int swz = (bid & 7) * q + (bid >> 3);
  int mt = swz >> 1, nt = swz & 1;          // NT = 2
  int mb = mt << 7, nb = nt << 7;
  int t = threadIdx.x, lane = t & 63, wid = t >> 6;
  int laneg = lane & 15, lk = lane >> 4;
  __shared__ __align__(16) u8 lA[128][256];
  __shared__ __align__(16) u8 lW[128][256];
  {
    int rl = lane >> 4;                     // 0..3 row within 4-row round
    int unit = lane & 15;
#pragma unroll
    for (int i = 0; i < 8; ++i) {
      int rb4 = ((wid << 3) + i) << 2;      // 4-row block base
      int r = rb4 + rl;
      int usA = unit ^ (r & 7);
      gl_lds16(A + (mb + r) * 256 + (usA << 4), &lA[rb4][0]);
      gl_lds16(W + (nb + r) * 256 + (usA << 4), &lW[rb4][0]);
    }
  }
  __syncthreads();
  f4v acc[4][4] = {};
  int wm = wid >> 1, wn = wid & 1;
#pragma unroll
  for (int kk = 0; kk < 8; ++kk) {
    ll8 af[4], bf[4];
#pragma unroll
    for (int m = 0; m < 4; ++m) {
      int r = (wm << 6) + (m << 4) + laneg;
      int us = ((kk << 1) + (lk >> 1)) ^ (r & 7);
      af[m] = *(const ll8*)&lA[r][(us << 4) + ((lk & 1) << 3)];
    }
#pragma unroll
    for (int n = 0; n < 4; ++n) {
      int r = (wn << 6) + (n << 4) + laneg;
      int us = ((kk << 1) + (lk >> 1)) ^ (r & 7);
      bf[n] = *(const ll8*)&lW[r][(us << 4) + ((lk & 1) << 3)];
    }
#pragma unroll
    for (int m = 0; m < 4; ++m)
#pragma unroll
      for (int n = 0; n < 4; ++n)
        acc[m][n] = __builtin_amdgcn_mfma_f32_16x16x32_fp8_fp8(af[m], bf[n], acc[m][n], 0, 0, 0);
  }
#pragma unroll
  for (int n = 0; n < 4; ++n) {
    int col = nb + (wn << 6) + (n << 4) + laneg;
    float csum = 0.f;
#pragma unroll
    for (int m = 0; m < 4; ++m) {
      int row0 = mb + (wm << 6) + (m << 4) + (lk << 2);
#pragma unroll
      for (int j = 0; j < 4; ++j) {
        float e = ex2(acc[m][n][j]);
        csum += e;
        out[(row0 + j) * 256 + col] = f2f8(e);
      }
    }
    csum += __shfl_xor(csum, 16);
    csum += __shfl_xor(csum, 32);
    if (lk == 0) atomicAdd(&Zsum[((mb >> 12) << 8) + col], csum);
  }
}

// ------- FUSED biLSTM v7: fp8 datapath + software-pipelined Wih·x (nacc one step ahead).
//         4 x-buffers (prefetch distance 3), vmcnt(4) guard, lgkm-only barrier. -------
// X8: fp8 [seq*64+t][256]; Wi8: fp8 [2][512][256]; Wh8d: fp8 [2][512][128]; out fp8.
__global__ __launch_bounds__(512, 1) void k_recur_f(const u8* __restrict__ X8,
                                                    const u8* __restrict__ Wi8,
                                                    const u8* __restrict__ Wh8d,
                                                    const float* __restrict__ bias_f,
                                                    const float* __restrict__ bias_b,
                                                    u8* __restrict__ outb) {
  int dir = blockIdx.y;
  int s0 = blockIdx.x << 4;                 // 16 sequences per block
  int t = threadIdx.x, lane = t & 63, w = t >> 6;  // 8 waves
  int laneg = lane & 15, lk = lane >> 4;
  const u8* Wd = Wh8d + dir * 65536;
  const u8* Wi = Wi8 + dir * 131072;
  const float* bia = dir ? bias_b : bias_f;
  int hc = w << 4;
  // Whh B-fragments, fp8 (K=128): 32 VGPR
  ll8 bfr[4][4];
#pragma unroll
  for (int g = 0; g < 4; ++g)
#pragma unroll
    for (int kk = 0; kk < 4; ++kk)
      bfr[g][kk] = *(const ll8*)(Wd + (g * 128 + hc + laneg) * 128 + kk * 32 + lk * 8);
  // Wih B-fragments, fp8 (K=256): 64 VGPR
  ll8 ifr[4][8];
#pragma unroll
  for (int g = 0; g < 4; ++g)
#pragma unroll
    for (int kk = 0; kk < 8; ++kk)
      ifr[g][kk] = *(const ll8*)(Wi + (g * 128 + hc + laneg) * 256 + kk * 32 + lk * 8);
  float bval[4];
#pragma unroll
  for (int g = 0; g < 4; ++g)
    bval[g] = bia[g * 128 + hc + laneg] * ((g == 2) ? GS_G : GS_IFO);

  __shared__ __align__(16) u8 hb[2][16][144];   // fp8 h double-buffer
  __shared__ __align__(16) u8 xb[4][16][256];   // fp8 x tiles, 16 KB (dist-3 prefetch)
  for (int i = t; i < 2 * 16 * 144; i += 512) ((u8*)hb)[i] = 0;

  float cs[4] = {0.f, 0.f, 0.f, 0.f};
  int tc0 = dir ? 63 : 0;
  int dstep = dir ? -1 : 1;
  // fp8 x staging: waves 0-3, 4 rows each (1024B per gl_lds instr, linear dest)
  int srw = (w << 2) + (lane >> 4);         // 0..15 for w<4
  int c16 = lane & 15;
  const u8* xsrc = X8 + (s0 + srw) * 16384 + ((c16 ^ (srw & 7)) << 4);
  // h-store lane mapping: 512 threads cover 16 rows x 32 u32-chunks
  int srow = t >> 5;                        // 0..15
  int schunk = t & 31;                      // 0..31
  int rowb = ((s0 >> 6) << 12) + (s0 & 63);
  // prologue: stage steps 0,1,2 into xb[0..2]; full drain once.
  if (w < 4) {
    gl_lds16(xsrc + tc0 * 256, &xb[0][w << 2][0]);
    gl_lds16(xsrc + (tc0 + dstep) * 256, &xb[1][w << 2][0]);
    gl_lds16(xsrc + (tc0 + 2 * dstep) * 256, &xb[2][w << 2][0]);
  }
  __syncthreads();
  // prologue: nacc = bias + Wih.x(step 0)
  f4v nacc[4];
#pragma unroll
  for (int g = 0; g < 4; ++g)
    nacc[g] = (f4v){bval[g], bval[g], bval[g], bval[g]};
  {
    const u8* xrow = &xb[0][laneg][0];
    ll8 xf[8];
#pragma unroll
    for (int kk = 0; kk < 8; ++kk)
      xf[kk] = *(const ll8*)&xrow[((((kk << 1) + (lk >> 1)) ^ (laneg & 7)) << 4) + ((lk & 1) << 3)];
#pragma unroll
    for (int g = 0; g < 4; ++g)
#pragma unroll
      for (int kk = 0; kk < 8; ++kk)
        nacc[g] = __builtin_amdgcn_mfma_f32_16x16x32_fp8_fp8(xf[kk], ifr[g][kk], nacc[g], 0, 0, 0);
  }
  int cur = 0;
  for (int st = 0; st < 64; ++st) {
    int tc = tc0 + st * dstep;
    // 0. take over pipelined accumulator (bias + Wih.x_t already in)
    f4v acc[4];
#pragma unroll
    for (int g = 0; g < 4; ++g) acc[g] = nacc[g];
    // 1. store h of previous step (reads hb[cur]; this step's writes go to hb[cur^1])
    if (st) {
      int pr = tc - dstep;
      u32 hv = *(const u32*)&hb[cur][srow][schunk << 2];
      *(u32*)(outb + (rowb + pr * 64 + srow) * 256 + (dir << 7) + (schunk << 2)) = hv;
    }
    // 2. prefetch step st+3 into xb[(st+3)&3] (that buffer last read at step st-2)
    if (w < 4 && st < 61) {
      gl_lds16(xsrc + (tc0 + (st + 3) * dstep) * 256, &xb[(st + 3) & 3][w << 2][0]);
    }
    // 3. serial chain: Whh·h (fp8 MFMA)
    {
      ll8 afr[4];
#pragma unroll
      for (int kk = 0; kk < 4; ++kk)
        afr[kk] = *(const ll8*)&hb[cur][laneg][kk * 32 + lk * 8];
#pragma unroll
      for (int g = 0; g < 4; ++g)
#pragma unroll
        for (int kk = 0; kk < 4; ++kk)
          acc[g] = __builtin_amdgcn_mfma_f32_16x16x32_fp8_fp8(afr[kk], bfr[g][kk], acc[g], 0, 0, 0);
    }
    // 4. INDEPENDENT: nacc = bias + Wih.x_{t+1} (fills the h-chain + gate shadow).
    //    xb[(st+1)&3] was staged by gl_lds at step st-2 (or prologue); vmcnt(4) leaves
    //    the 4 newer per-wave VMEM ops (store/gl of st-1 and st) in flight.
    if (st < 63) {
      asm volatile("s_waitcnt vmcnt(4)" ::: "memory");
#pragma unroll
      for (int g = 0; g < 4; ++g)
        nacc[g] = (f4v){bval[g], bval[g], bval[g], bval[g]};
      const u8* xrow = &xb[(st + 1) & 3][laneg][0];
      ll8 xf[8];
#pragma unroll
      for (int kk = 0; kk < 8; ++kk)
        xf[kk] = *(const ll8*)&xrow[((((kk << 1) + (lk >> 1)) ^ (laneg & 7)) << 4) + ((lk & 1) << 3)];
#pragma unroll
      for (int g = 0; g < 4; ++g)
#pragma unroll
        for (int kk = 0; kk < 8; ++kk)
          nacc[g] = __builtin_amdgcn_mfma_f32_16x16x32_fp8_fp8(xf[kk], ifr[g][kk], nacc[g], 0, 0, 0);
    }
    // 5. gates (8 trans/h): tanh(x)=(X-1)/(X+1), shared-rcp products
    int nxt = cur ^ 1;
#pragma unroll
    for (int j = 0; j < 4; ++j) {
      float Y = ex2(-acc[0][j]);            // i-gate
      float V = ex2(-acc[1][j]);            // f-gate
      float X = ex2(acc[2][j]);             // g-gate (2x log2e folded)
      float W = ex2(-acc[3][j]);            // o-gate
      float ig = (X - 1.0f) * rcpf((1.0f + Y) * (X + 1.0f));
      float c = cs[j] * rcpf(1.0f + V) + ig;
      cs[j] = c;
      float Z = ex2(c * GS_G);
      float h = (Z - 1.0f) * rcpf((1.0f + W) * (Z + 1.0f));
      hb[nxt][(lk << 2) + j][hc + laneg] = f2f8(h);
    }
    // 6. LDS-only barrier (global write-acks and young prefetches stay in flight)
    asm volatile("s_waitcnt lgkmcnt(0)" ::: "memory");
    __builtin_amdgcn_s_barrier();
    cur = nxt;
  }
  // final h store
  {
    int pr = tc0 + 63 * dstep;
    u32 hv = *(const u32*)&hb[cur][srow][schunk << 2];
    *(u32*)(outb + (rowb + pr * 64 + srow) * 256 + (dir << 7) + (schunk << 2)) = hv;
  }
}

// ------- fused attention + final: att = (qavg/Z) . evf(fp8) ; out = in*(1+al*sig(att)) ----
__global__ __launch_bounds__(256) void k_attfin(const u8* __restrict__ VF8,
                                                const float* __restrict__ qavg,
                                                const float* __restrict__ Z,
                                                const float* __restrict__ in,
                                                const float* __restrict__ alpha,
                                                float* __restrict__ out) {
  int bx = blockIdx.x;
  int b = bx >> 6;
  int sp0 = (bx & 63) << 6;
  int t = threadIdx.x, lane = t & 63, wid = t >> 6;
  __shared__ __align__(16) float lwo[256];
  __shared__ float fac[64];
  lwo[t] = qavg[b * 256 + t] / Z[b * 256 + t];
  __syncthreads();
  float4 wo = *(const float4*)&lwo[lane * 4];
  int rowbase = b * 4096 + sp0;
#pragma unroll 4
  for (int i = 0; i < 16; ++i) {
    int r = wid * 16 + i;
    u32 v = *(const u32*)&VF8[(rowbase + r) * 256 + lane * 4];
    float p = wo.x * f8tof<0>(v) + wo.y * f8tof<1>(v) +
              wo.z * f8tof<2>(v) + wo.w * f8tof<3>(v);
#pragma unroll
    for (int off = 32; off; off >>= 1) p += __shfl_xor(p, off);
    if (lane == 0) fac[r] = p;
  }
  __syncthreads();
  float al = alpha[0];
  if (t < 64) fac[t] = 1.0f + al * sigf(fac[t]);
  __syncthreads();
  int sp = t & 63;
  float f = fac[sp];
  const float* ip = in + (long)b * 1048576 + sp0 + sp;
  float* op = out + (long)b * 1048576 + sp0 + sp;
  int c0 = t >> 6;
#pragma unroll 8
  for (int c = c0; c < 256; c += 4) {
    op[c * 4096] = ip[c * 4096] * f;
  }
}

extern "C" void kernel_launch(void* const* d_in, const int* in_sizes, int n_in,
                              void* d_out, int out_size, void* d_ws, size_t ws_size,
                              hipStream_t stream) {
  const float* input   = (const float*)d_in[0];
  const float* h_Wih_f = (const float*)d_in[1];
  const float* h_Whh_f = (const float*)d_in[2];
  const float* h_b_f   = (const float*)d_in[3];
  const float* h_Wih_b = (const float*)d_in[4];
  const float* h_Whh_b = (const float*)d_in[5];
  const float* h_b_b   = (const float*)d_in[6];
  const float* v_Wih_f = (const float*)d_in[7];
  const float* v_Whh_f = (const float*)d_in[8];
  const float* v_b_f   = (const float*)d_in[9];
  const float* v_Wih_b = (const float*)d_in[10];
  const float* v_Whh_b = (const float*)d_in[11];
  const float* v_b_b   = (const float*)d_in[12];
  const float* Wr      = (const float*)d_in[13];
  const float* Wl      = (const float*)d_in[14];
  const float* alphap  = (const float*)d_in[15];

  char* ws = (char*)d_ws;
  u8*  Ah8   = (u8*)(ws + 0);              // 16,777,216 B fp8 x (stage1); later Ar8
  u8*  VF8   = (u8*)(ws + 33554432);       // 16,777,216 B fp8 evf
  u8*  Wh8   = (u8*)(ws + 67108864);       // 262,144 fp8 [2][512][256]
  u8*  Wv8   = (u8*)(ws + 67371008);       // 262,144
  u8*  WhhH8 = (u8*)(ws + 67633152);       // 131,072 fp8 [2][512][128]
  u8*  WhhV8 = (u8*)(ws + 67764224);       // 131,072
  u8*  Wrb8  = (u8*)(ws + 67895296);       // 65,536 fp8 [256][256]
  float* meansum = (float*)(ws + 67960832);  // 16 KB
  float* qavg    = (float*)(ws + 67977216);  // 16 KB
  float* pZ      = (float*)(ws + 67993600);  // 16 KB
  u8*  Av8 = (u8*)d_out;                   // stage1 fp8 output (16.7MB, dead before attfin)
  u8*  Ar8 = Ah8;                          // stage2 fp8 output over dead Ah8

  (void)hipMemsetAsync(meansum, 0, 3 * 16384, stream);  // meansum + qavg + pZ

  CvtArgs ca;
  ca.src[0] = h_Wih_f; ca.dst[0] = Wh8;           ca.n4[0] = 32768; ca.scl[0] = 1; ca.sh[0] = 6;
  ca.src[1] = h_Wih_b; ca.dst[1] = Wh8 + 131072;  ca.n4[1] = 32768; ca.scl[1] = 1; ca.sh[1] = 6;
  ca.src[2] = v_Wih_f; ca.dst[2] = Wv8;           ca.n4[2] = 32768; ca.scl[2] = 1; ca.sh[2] = 6;
  ca.src[3] = v_Wih_b; ca.dst[3] = Wv8 + 131072;  ca.n4[3] = 32768; ca.scl[3] = 1; ca.sh[3] = 6;
  ca.src[4] = h_Whh_f; ca.dst[4] = WhhH8;         ca.n4[4] = 16384; ca.scl[4] = 1; ca.sh[4] = 5;
  ca.src[5] = h_Whh_b; ca.dst[5] = WhhH8 + 65536; ca.n4[5] = 16384; ca.scl[5] = 1; ca.sh[5] = 5;
  ca.src[6] = v_Whh_f; ca.dst[6] = WhhV8;         ca.n4[6] = 16384; ca.scl[6] = 1; ca.sh[6] = 5;
  ca.src[7] = v_Whh_b; ca.dst[7] = WhhV8 + 65536; ca.n4[7] = 16384; ca.scl[7] = 1; ca.sh[7] = 5;
  ca.src[8] = Wr;      ca.dst[8] = Wrb8;          ca.n4[8] = 16384; ca.scl[8] = 2; ca.sh[8] = 6;
  k_cvt<<<dim3(128, 9), 256, 0, stream>>>(ca);

  k_tin<<<dim3(4, 64, 16), 256, 0, stream>>>(input, Ah8, meansum);
  k_qavg<<<16, 256, 0, stream>>>(meansum, Wl, qavg);

  k_recur_f<<<dim3(64, 2), 512, 0, stream>>>(Ah8, Wh8, WhhH8, h_b_f, h_b_b, Av8);
  k_recur_f<<<dim3(64, 2), 512, 0, stream>>>(Av8, Wv8, WhhV8, v_b_f, v_b_b, Ar8);
  k_gemm8<<<1024, 256, 0, stream>>>(Ar8, Wrb8, VF8, pZ);

  k_attfin<<<1024, 256, 0, stream>>>(VF8, qavg, pZ, input, alphap, (float*)d_out);
}

// Round 16
// 299.474 us; speedup vs baseline: 2.2388x; 1.0260x over previous
//
#include <hip/hip_runtime.h>
#include <hip/hip_bf16.h>

typedef unsigned short u16;
typedef unsigned int u32;
typedef unsigned char u8;
typedef long long ll8;                                   // 8 x fp8 operand
typedef __attribute__((ext_vector_type(4))) float f4v;   // mfma acc

__device__ __forceinline__ float rcpf(float x) { return __builtin_amdgcn_rcpf(x); }
__device__ __forceinline__ float ex2(float x) {
#if __has_builtin(__builtin_amdgcn_exp2f)
  return __builtin_amdgcn_exp2f(x);
#else
  return exp2f(x);
#endif
}
__device__ __forceinline__ float sigf(float x) { return rcpf(1.0f + __expf(-x)); }
// pack 2 floats -> 2 fp8 e4m3 bytes into low/high 16b word of old (HI immediate)
template<bool HI>
__device__ __forceinline__ u32 pkfp8(float a, float b, u32 old) {
  return (u32)__builtin_amdgcn_cvt_pk_fp8_f32(a, b, (int)old, HI);
}
__device__ __forceinline__ u8 f2f8(float x) { return (u8)(pkfp8<false>(x, x, 0) & 0xffu); }
// fp8 e4m3 byte (selected from u32) -> f32
template<int S>
__device__ __forceinline__ float f8tof(u32 v) {
#if __has_builtin(__builtin_amdgcn_cvt_f32_fp8)
  return __builtin_amdgcn_cvt_f32_fp8((int)v, S);
#else
  u8 b = (u8)(v >> (8 * S));
  u32 s = (b >> 7) & 1u, e = (b >> 3) & 15u, m = b & 7u;
  union { u32 i; float f; } r;
  if (e) r.i = (s << 31) | ((e + 120u) << 23) | (m << 20);
  else { r.f = (float)m * 0.001953125f; r.i |= s << 31; }
  return r.f;
#endif
}

#define GS_IFO 1.4426950408889634f
#define GS_G   2.8853900817779268f

__device__ __forceinline__ void gl_lds16(const void* g, void* l) {
  __builtin_amdgcn_global_load_lds(
      (const __attribute__((address_space(1))) u32*)g,
      (__attribute__((address_space(3))) u32*)l, 16, 0, 0);
}

// ---------------- weight conversion fp32 -> fp8 (all weights) ----------------
struct CvtArgs {
  const float* src[9];
  u8* dst[9];
  int n4[9];
  int scl[9];
  int sh[9];
};
__global__ __launch_bounds__(256) void k_cvt(CvtArgs a) {
  int seg = blockIdx.y;
  int i = blockIdx.x * 256 + threadIdx.x;
  if (i >= a.n4[seg]) return;
  float4 v = ((const float4*)a.src[seg])[i];
  float s;
  if (a.scl[seg] == 2) {
    s = GS_IFO;
  } else {
    int r = i >> a.sh[seg];
    s = (((r >> 7) & 3) == 2) ? GS_G : GS_IFO;
  }
  v.x *= s; v.y *= s; v.z *= s; v.w *= s;
  u32 p = pkfp8<false>(v.x, v.y, 0);
  p = pkfp8<true>(v.z, v.w, p);
  ((u32*)a.dst[seg])[i] = p;
}

// ------- transpose input [B,C,H,W] -> fp8 x [(b,w,h)][c]; also channel sums -------
__global__ __launch_bounds__(256) void k_tin(const float* __restrict__ in,
                                             u8* __restrict__ A8,
                                             float* __restrict__ meansum) {
  int b = blockIdx.z, h = blockIdx.y, c0 = blockIdx.x * 64;
  int t = threadIdx.x, lane = t & 63, q = t >> 6;
  __shared__ u8 lT[64][68];
  const float* src = in + ((b * 256 + c0) * 64 + h) * 64;
#pragma unroll 4
  for (int i = 0; i < 16; ++i) {
    int cl = q * 16 + i;
    float v = src[cl * 4096 + lane];
    lT[cl][lane] = f2f8(v);
    float s = v;
#pragma unroll
    for (int off = 32; off; off >>= 1) s += __shfl_xor(s, off);
    if (lane == 0) atomicAdd(&meansum[b * 256 + c0 + cl], s);
  }
  __syncthreads();
  u8* dst = A8 + (b * 4096 + h) * 256 + c0;
#pragma unroll 4
  for (int i = 0; i < 16; ++i) {
    int w = q * 16 + i;
    dst[w * 16384 + lane] = lT[lane][w];
  }
}

// ------- q_avg[b][o] = softmax_o( Wl[o,:] . mean_c ) -------
__global__ __launch_bounds__(256) void k_qavg(const float* __restrict__ meansum,
                                              const float* __restrict__ Wl,
                                              float* __restrict__ qavg) {
  int b = blockIdx.x, t = threadIdx.x;
  __shared__ float mean[256];
  __shared__ float red[256];
  mean[t] = meansum[b * 256 + t] * (1.0f / 4096.0f);
  __syncthreads();
  const float* wr = Wl + t * 256;
  float acc = 0.0f;
  for (int c = 0; c < 256; ++c) acc = fmaf(wr[c], mean[c], acc);
  red[t] = acc; __syncthreads();
  for (int s = 128; s; s >>= 1) { if (t < s) red[t] = fmaxf(red[t], red[t + s]); __syncthreads(); }
  float mx = red[0]; __syncthreads();
  float e = __expf(acc - mx);
  red[t] = e; __syncthreads();
  for (int s = 128; s; s >>= 1) { if (t < s) red[t] += red[t + s]; __syncthreads(); }
  qavg[b * 256 + t] = e / red[0];
}

// ------- 128x128 fp8 GEMM, full-K resident (Wr path): VF=fp8(exp2(A.W)), Zsum atomics ----
__global__ __launch_bounds__(256, 2) void k_gemm8(const u8* __restrict__ A,
                                                  const u8* __restrict__ W,
                                                  u8* __restrict__ out,
                                                  float* __restrict__ Zsum) {
  int nwg = gridDim.x;
  int q = nwg >> 3;
  int bid = blockIdx.x;
  int swz = (bid & 7) * q + (bid >> 3);
  int mt = swz >> 1, nt = swz & 1;          // NT = 2
  int mb = mt << 7, nb = nt << 7;
  int t = threadIdx.x, lane = t & 63, wid = t >> 6;
  int laneg = lane & 15, lk = lane >> 4;
  __shared__ __align__(16) u8 lA[128][256];
  __shared__ __align__(16) u8 lW[128][256];
  {
    int rl = lane >> 4;                     // 0..3 row within 4-row round
    int unit = lane & 15;
#pragma unroll
    for (int i = 0; i < 8; ++i) {
      int rb4 = ((wid << 3) + i) << 2;      // 4-row block base
      int r = rb4 + rl;
      int usA = unit ^ (r & 7);
      gl_lds16(A + (mb + r) * 256 + (usA << 4), &lA[rb4][0]);
      gl_lds16(W + (nb + r) * 256 + (usA << 4), &lW[rb4][0]);
    }
  }
  __syncthreads();
  f4v acc[4][4] = {};
  int wm = wid >> 1, wn = wid & 1;
#pragma unroll
  for (int kk = 0; kk < 8; ++kk) {
    ll8 af[4], bf[4];
#pragma unroll
    for (int m = 0; m < 4; ++m) {
      int r = (wm << 6) + (m << 4) + laneg;
      int us = ((kk << 1) + (lk >> 1)) ^ (r & 7);
      af[m] = *(const ll8*)&lA[r][(us << 4) + ((lk & 1) << 3)];
    }
#pragma unroll
    for (int n = 0; n < 4; ++n) {
      int r = (wn << 6) + (n << 4) + laneg;
      int us = ((kk << 1) + (lk >> 1)) ^ (r & 7);
      bf[n] = *(const ll8*)&lW[r][(us << 4) + ((lk & 1) << 3)];
    }
#pragma unroll
    for (int m = 0; m < 4; ++m)
#pragma unroll
      for (int n = 0; n < 4; ++n)
        acc[m][n] = __builtin_amdgcn_mfma_f32_16x16x32_fp8_fp8(af[m], bf[n], acc[m][n], 0, 0, 0);
  }
#pragma unroll
  for (int n = 0; n < 4; ++n) {
    int col = nb + (wn << 6) + (n << 4) + laneg;
    float csum = 0.f;
#pragma unroll
    for (int m = 0; m < 4; ++m) {
      int row0 = mb + (wm << 6) + (m << 4) + (lk << 2);
#pragma unroll
      for (int j = 0; j < 4; ++j) {
        float e = ex2(acc[m][n][j]);
        csum += e;
        out[(row0 + j) * 256 + col] = f2f8(e);
      }
    }
    csum += __shfl_xor(csum, 16);
    csum += __shfl_xor(csum, 32);
    if (lk == 0) atomicAdd(&Zsum[((mb >> 12) << 8) + col], csum);
  }
}

// ------- FUSED biLSTM v8: fp8 datapath, 2-step-unrolled nacc ping-pong (no acc copies),
//         setprio around h-MFMA, vmcnt(2) guard, lgkm-only barrier. -------
__global__ __launch_bounds__(512, 1) void k_recur_f(const u8* __restrict__ X8,
                                                    const u8* __restrict__ Wi8,
                                                    const u8* __restrict__ Wh8d,
                                                    const float* __restrict__ bias_f,
                                                    const float* __restrict__ bias_b,
                                                    u8* __restrict__ outb) {
  int dir = blockIdx.y;
  int s0 = blockIdx.x << 4;                 // 16 sequences per block
  int t = threadIdx.x, lane = t & 63, w = t >> 6;  // 8 waves
  int laneg = lane & 15, lk = lane >> 4;
  const u8* Wd = Wh8d + dir * 65536;
  const u8* Wi = Wi8 + dir * 131072;
  const float* bia = dir ? bias_b : bias_f;
  int hc = w << 4;
  // Whh B-fragments, fp8 (K=128): 32 VGPR
  ll8 bfr[4][4];
#pragma unroll
  for (int g = 0; g < 4; ++g)
#pragma unroll
    for (int kk = 0; kk < 4; ++kk)
      bfr[g][kk] = *(const ll8*)(Wd + (g * 128 + hc + laneg) * 128 + kk * 32 + lk * 8);
  // Wih B-fragments, fp8 (K=256): 64 VGPR
  ll8 ifr[4][8];
#pragma unroll
  for (int g = 0; g < 4; ++g)
#pragma unroll
    for (int kk = 0; kk < 8; ++kk)
      ifr[g][kk] = *(const ll8*)(Wi + (g * 128 + hc + laneg) * 256 + kk * 32 + lk * 8);
  float bval[4];
#pragma unroll
  for (int g = 0; g < 4; ++g)
    bval[g] = bia[g * 128 + hc + laneg] * ((g == 2) ? GS_G : GS_IFO);

  __shared__ __align__(16) u8 hb[2][16][144];   // fp8 h double-buffer
  __shared__ __align__(16) u8 xb[4][16][256];   // fp8 x tiles (dist-3 prefetch)
  for (int i = t; i < 2 * 16 * 144; i += 512) ((u8*)hb)[i] = 0;

  float cs[4] = {0.f, 0.f, 0.f, 0.f};
  int tc0 = dir ? 63 : 0;
  int dstep = dir ? -1 : 1;
  // fp8 x staging: waves 0-3, 4 rows each (1024B per gl_lds instr, linear dest)
  int srw = (w << 2) + (lane >> 4);         // 0..15 for w<4
  int c16 = lane & 15;
  const u8* xsrc = X8 + (s0 + srw) * 16384 + ((c16 ^ (srw & 7)) << 4);
  // h-store lane mapping: 512 threads cover 16 rows x 32 u32-chunks
  int srow = t >> 5;                        // 0..15
  int schunk = t & 31;                      // 0..31
  int rowb = ((s0 >> 6) << 12) + (s0 & 63);

  // helpers as lambdas (inlined)
  auto wihx = [&](f4v (&a)[4], const u8* xrow) {
    ll8 xf[8];
#pragma unroll
    for (int kk = 0; kk < 8; ++kk)
      xf[kk] = *(const ll8*)&xrow[((((kk << 1) + (lk >> 1)) ^ (laneg & 7)) << 4) + ((lk & 1) << 3)];
#pragma unroll
    for (int g = 0; g < 4; ++g)
#pragma unroll
      for (int kk = 0; kk < 8; ++kk)
        a[g] = __builtin_amdgcn_mfma_f32_16x16x32_fp8_fp8(xf[kk], ifr[g][kk], a[g], 0, 0, 0);
  };

  // prologue: stage x(steps 0,1,2); full drain; build naccP(x0), naccQ(x1)
  if (w < 4) {
    gl_lds16(xsrc + tc0 * 256, &xb[0][w << 2][0]);
    gl_lds16(xsrc + (tc0 + dstep) * 256, &xb[1][w << 2][0]);
    gl_lds16(xsrc + (tc0 + 2 * dstep) * 256, &xb[2][w << 2][0]);
  }
  __syncthreads();
  f4v naccP[4], naccQ[4];
#pragma unroll
  for (int g = 0; g < 4; ++g) {
    naccP[g] = (f4v){bval[g], bval[g], bval[g], bval[g]};
    naccQ[g] = naccP[g];
  }
  wihx(naccP, &xb[0][laneg][0]);
  wihx(naccQ, &xb[1][laneg][0]);

  int cur = 0;
  for (int st = 0; st < 64; st += 2) {
    // ================= even step st (consumes naccP) =================
    {
      int tc = tc0 + st * dstep;
      if (st) {
        int pr = tc - dstep;
        u32 hv = *(const u32*)&hb[cur][srow][schunk << 2];
        *(u32*)(outb + (rowb + pr * 64 + srow) * 256 + (dir << 7) + (schunk << 2)) = hv;
      }
      if (w < 4 && st < 61)
        gl_lds16(xsrc + (tc0 + (st + 3) * dstep) * 256, &xb[(st + 3) & 3][w << 2][0]);
      // h-MFMA chain into naccP
      __builtin_amdgcn_s_setprio(1);
      {
        ll8 afr[4];
#pragma unroll
        for (int kk = 0; kk < 4; ++kk)
          afr[kk] = *(const ll8*)&hb[cur][laneg][kk * 32 + lk * 8];
#pragma unroll
        for (int g = 0; g < 4; ++g)
#pragma unroll
          for (int kk = 0; kk < 4; ++kk)
            naccP[g] = __builtin_amdgcn_mfma_f32_16x16x32_fp8_fp8(afr[kk], bfr[g][kk], naccP[g], 0, 0, 0);
      }
      __builtin_amdgcn_s_setprio(0);
      // gates consume naccP
      int nxt = cur ^ 1;
#pragma unroll
      for (int j = 0; j < 4; ++j) {
        float Y = ex2(-naccP[j == 0 ? 0 : 0][j]);  // placeholder avoided below
        (void)Y;
      }
      // (explicit gate block; written out to keep per-gate indexing clear)
#pragma unroll
      for (int j = 0; j < 4; ++j) {
        float Y = ex2(-naccP[0][j]);
        float V = ex2(-naccP[1][j]);
        float X = ex2(naccP[2][j]);
        float Wo = ex2(-naccP[3][j]);
        float ig = (X - 1.0f) * rcpf((1.0f + Y) * (X + 1.0f));
        float c = cs[j] * rcpf(1.0f + V) + ig;
        cs[j] = c;
        float Z = ex2(c * GS_G);
        float h = (Z - 1.0f) * rcpf((1.0f + Wo) * (Z + 1.0f));
        hb[nxt][(lk << 2) + j][hc + laneg] = f2f8(h);
      }
      // rebuild naccP for st+2 (x staged 1+ steps ago)
      if (st < 62) {
        if (st == 0) { asm volatile("s_waitcnt vmcnt(1)" ::: "memory"); }
        else         { asm volatile("s_waitcnt vmcnt(2)" ::: "memory"); }
#pragma unroll
        for (int g = 0; g < 4; ++g)
          naccP[g] = (f4v){bval[g], bval[g], bval[g], bval[g]};
        wihx(naccP, &xb[(st + 2) & 3][laneg][0]);
      }
      asm volatile("s_waitcnt lgkmcnt(0)" ::: "memory");
      __builtin_amdgcn_s_barrier();
      cur = nxt;
    }
    // ================= odd step st+1 (consumes naccQ) =================
    {
      int so = st + 1;
      int tc = tc0 + so * dstep;
      {
        int pr = tc - dstep;
        u32 hv = *(const u32*)&hb[cur][srow][schunk << 2];
        *(u32*)(outb + (rowb + pr * 64 + srow) * 256 + (dir << 7) + (schunk << 2)) = hv;
      }
      if (w < 4 && so < 61)
        gl_lds16(xsrc + (tc0 + (so + 3) * dstep) * 256, &xb[(so + 3) & 3][w << 2][0]);
      __builtin_amdgcn_s_setprio(1);
      {
        ll8 afr[4];
#pragma unroll
        for (int kk = 0; kk < 4; ++kk)
          afr[kk] = *(const ll8*)&hb[cur][laneg][kk * 32 + lk * 8];
#pragma unroll
        for (int g = 0; g < 4; ++g)
#pragma unroll
          for (int kk = 0; kk < 4; ++kk)
            naccQ[g] = __builtin_amdgcn_mfma_f32_16x16x32_fp8_fp8(afr[kk], bfr[g][kk], naccQ[g], 0, 0, 0);
      }
      __builtin_amdgcn_s_setprio(0);
      int nxt = cur ^ 1;
#pragma unroll
      for (int j = 0; j < 4; ++j) {
        float Y = ex2(-naccQ[0][j]);
        float V = ex2(-naccQ[1][j]);
        float X = ex2(naccQ[2][j]);
        float Wo = ex2(-naccQ[3][j]);
        float ig = (X - 1.0f) * rcpf((1.0f + Y) * (X + 1.0f));
        float c = cs[j] * rcpf(1.0f + V) + ig;
        cs[j] = c;
        float Z = ex2(c * GS_G);
        float h = (Z - 1.0f) * rcpf((1.0f + Wo) * (Z + 1.0f));
        hb[nxt][(lk << 2) + j][hc + laneg] = f2f8(h);
      }
      if (so < 62) {
        asm volatile("s_waitcnt vmcnt(2)" ::: "memory");
#pragma unroll
        for (int g = 0; g < 4; ++g)
          naccQ[g] = (f4v){bval[g], bval[g], bval[g], bval[g]};
        wihx(naccQ, &xb[(so + 2) & 3][laneg][0]);
      }
      asm volatile("s_waitcnt lgkmcnt(0)" ::: "memory");
      __builtin_amdgcn_s_barrier();
      cur = nxt;
    }
  }
  // final h store (h of step 63 sits in hb[cur])
  {
    int pr = tc0 + 63 * dstep;
    u32 hv = *(const u32*)&hb[cur][srow][schunk << 2];
    *(u32*)(outb + (rowb + pr * 64 + srow) * 256 + (dir << 7) + (schunk << 2)) = hv;
  }
}

// ------- fused attention + final: att = (qavg/Z) . evf(fp8) ; out = in*(1+al*sig(att)) ----
__global__ __launch_bounds__(256) void k_attfin(const u8* __restrict__ VF8,
                                                const float* __restrict__ qavg,
                                                const float* __restrict__ Z,
                                                const float* __restrict__ in,
                                                const float* __restrict__ alpha,
                                                float* __restrict__ out) {
  int bx = blockIdx.x;
  int b = bx >> 6;
  int sp0 = (bx & 63) << 6;
  int t = threadIdx.x, lane = t & 63, wid = t >> 6;
  __shared__ __align__(16) float lwo[256];
  __shared__ float fac[64];
  lwo[t] = qavg[b * 256 + t] / Z[b * 256 + t];
  __syncthreads();
  float4 wo = *(const float4*)&lwo[lane * 4];
  int rowbase = b * 4096 + sp0;
#pragma unroll 4
  for (int i = 0; i < 16; ++i) {
    int r = wid * 16 + i;
    u32 v = *(const u32*)&VF8[(rowbase + r) * 256 + lane * 4];
    float p = wo.x * f8tof<0>(v) + wo.y * f8tof<1>(v) +
              wo.z * f8tof<2>(v) + wo.w * f8tof<3>(v);
#pragma unroll
    for (int off = 32; off; off >>= 1) p += __shfl_xor(p, off);
    if (lane == 0) fac[r] = p;
  }
  __syncthreads();
  float al = alpha[0];
  if (t < 64) fac[t] = 1.0f + al * sigf(fac[t]);
  __syncthreads();
  int sp = t & 63;
  float f = fac[sp];
  const float* ip = in + (long)b * 1048576 + sp0 + sp;
  float* op = out + (long)b * 1048576 + sp0 + sp;
  int c0 = t >> 6;
#pragma unroll 8
  for (int c = c0; c < 256; c += 4) {
    op[c * 4096] = ip[c * 4096] * f;
  }
}

extern "C" void kernel_launch(void* const* d_in, const int* in_sizes, int n_in,
                              void* d_out, int out_size, void* d_ws, size_t ws_size,
                              hipStream_t stream) {
  const float* input   = (const float*)d_in[0];
  const float* h_Wih_f = (const float*)d_in[1];
  const float* h_Whh_f = (const float*)d_in[2];
  const float* h_b_f   = (const float*)d_in[3];
  const float* h_Wih_b = (const float*)d_in[4];
  const float* h_Whh_b = (const float*)d_in[5];
  const float* h_b_b   = (const float*)d_in[6];
  const float* v_Wih_f = (const float*)d_in[7];
  const float* v_Whh_f = (const float*)d_in[8];
  const float* v_b_f   = (const float*)d_in[9];
  const float* v_Wih_b = (const float*)d_in[10];
  const float* v_Whh_b = (const float*)d_in[11];
  const float* v_b_b   = (const float*)d_in[12];
  const float* Wr      = (const float*)d_in[13];
  const float* Wl      = (const float*)d_in[14];
  const float* alphap  = (const float*)d_in[15];

  char* ws = (char*)d_ws;
  u8*  Ah8   = (u8*)(ws + 0);              // 16,777,216 B fp8 x (stage1); later Ar8
  u8*  VF8   = (u8*)(ws + 33554432);       // 16,777,216 B fp8 evf
  u8*  Wh8   = (u8*)(ws + 67108864);       // 262,144 fp8 [2][512][256]
  u8*  Wv8   = (u8*)(ws + 67371008);       // 262,144
  u8*  WhhH8 = (u8*)(ws + 67633152);       // 131,072 fp8 [2][512][128]
  u8*  WhhV8 = (u8*)(ws + 67764224);       // 131,072
  u8*  Wrb8  = (u8*)(ws + 67895296);       // 65,536 fp8 [256][256]
  float* meansum = (float*)(ws + 67960832);  // 16 KB
  float* qavg    = (float*)(ws + 67977216);  // 16 KB
  float* pZ      = (float*)(ws + 67993600);  // 16 KB
  u8*  Av8 = (u8*)d_out;                   // stage1 fp8 output (16.7MB, dead before attfin)
  u8*  Ar8 = Ah8;                          // stage2 fp8 output over dead Ah8

  (void)hipMemsetAsync(meansum, 0, 3 * 16384, stream);  // meansum + qavg + pZ

  CvtArgs ca;
  ca.src[0] = h_Wih_f; ca.dst[0] = Wh8;           ca.n4[0] = 32768; ca.scl[0] = 1; ca.sh[0] = 6;
  ca.src[1] = h_Wih_b; ca.dst[1] = Wh8 + 131072;  ca.n4[1] = 32768; ca.scl[1] = 1; ca.sh[1] = 6;
  ca.src[2] = v_Wih_f; ca.dst[2] = Wv8;           ca.n4[2] = 32768; ca.scl[2] = 1; ca.sh[2] = 6;
  ca.src[3] = v_Wih_b; ca.dst[3] = Wv8 + 131072;  ca.n4[3] = 32768; ca.scl[3] = 1; ca.sh[3] = 6;
  ca.src[4] = h_Whh_f; ca.dst[4] = WhhH8;         ca.n4[4] = 16384; ca.scl[4] = 1; ca.sh[4] = 5;
  ca.src[5] = h_Whh_b; ca.dst[5] = WhhH8 + 65536; ca.n4[5] = 16384; ca.scl[5] = 1; ca.sh[5] = 5;
  ca.src[6] = v_Whh_f; ca.dst[6] = WhhV8;         ca.n4[6] = 16384; ca.scl[6] = 1; ca.sh[6] = 5;
  ca.src[7] = v_Whh_b; ca.dst[7] = WhhV8 + 65536; ca.n4[7] = 16384; ca.scl[7] = 1; ca.sh[7] = 5;
  ca.src[8] = Wr;      ca.dst[8] = Wrb8;          ca.n4[8] = 16384; ca.scl[8] = 2; ca.sh[8] = 6;
  k_cvt<<<dim3(128, 9), 256, 0, stream>>>(ca);

  k_tin<<<dim3(4, 64, 16), 256, 0, stream>>>(input, Ah8, meansum);
  k_qavg<<<16, 256, 0, stream>>>(meansum, Wl, qavg);

  k_recur_f<<<dim3(64, 2), 512, 0, stream>>>(Ah8, Wh8, WhhH8, h_b_f, h_b_b, Av8);
  k_recur_f<<<dim3(64, 2), 512, 0, stream>>>(Av8, Wv8, WhhV8, v_b_f, v_b_b, Ar8);
  k_gemm8<<<1024, 256, 0, stream>>>(Ar8, Wrb8, VF8, pZ);

  k_attfin<<<1024, 256, 0, stream>>>(VF8, qavg, pZ, input, alphap, (float*)d_out);
}